// Round 1
// baseline (1640.062 us; speedup 1.0000x reference)
//
#include <hip/hip_runtime.h>

#define Adim 4096
#define Mdim 6
#define HD 128
#define TSTEPS 30
#define NROWS 24576
#define RBLK 96
#define NBLKS 256           // NROWS / RBLK
#define DT_C 0.2f
#define SQDT_C 0.4472136f
#define LN_EPS 1e-5f

#define PI_OFF   2949120    // 6*4096*30*4
#define MASK_OFF 2973696    // PI_OFF + 24576

typedef unsigned short u16;
typedef __bf16 bf16x8 __attribute__((ext_vector_type(8)));
typedef float f32x4 __attribute__((ext_vector_type(4)));

__device__ __forceinline__ u16 f2bf(float x){
    unsigned u = __builtin_bit_cast(unsigned, x);
    u = (u + 0x7fffu + ((u >> 16) & 1u)) >> 16;
    return (u16)u;
}
__device__ __forceinline__ float bf2f(unsigned h){
    unsigned u = (h & 0xffffu) << 16;
    return __builtin_bit_cast(float, u);
}
__device__ __forceinline__ unsigned pack2(float a, float b){
    return (unsigned)f2bf(a) | ((unsigned)f2bf(b) << 16);
}
__device__ __forceinline__ float tanh_f(float x){
    return 1.0f - 2.0f / (1.0f + __expf(2.0f * x));
}
__device__ __forceinline__ float sigm_f(float x){
    return 1.0f / (1.0f + __expf(-x));
}
// XOR swizzle in u16 units within a row (conflict-free ds_read_b128)
#define SWZ(r,k) ((k) ^ (((r)&7)<<3))

// ---------- MFMA GEMM: 96 rows x 128 cols, K=128 slice ----------
// A: LDS bf16 [96][lda] swizzled; W: LDS bf16 image [col][k] swizzled.
// wave `ctile` owns cols [16*ctile, 16*ctile+16), 6 row tiles of 16.
__device__ __forceinline__ void gemm6(const u16* Ab, int lda, int kBase,
                                      const u16* Wb, int lane, int ctile,
                                      f32x4 acc[6], bool init)
{
    const int cl = lane & 15;
    const int kq = lane >> 4;
    const int c  = ctile * 16 + cl;
    bf16x8 bf[4];
#pragma unroll
    for (int kk = 0; kk < 4; ++kk)
        bf[kk] = *reinterpret_cast<const bf16x8*>(Wb + c * 128 + SWZ(c, kk*32 + kq*8));
#pragma unroll
    for (int tr = 0; tr < 6; ++tr) {
        const int r = tr * 16 + cl;
        bf16x8 af[4];
#pragma unroll
        for (int kk = 0; kk < 4; ++kk)
            af[kk] = *reinterpret_cast<const bf16x8*>(Ab + r * lda + SWZ(r, kBase + kk*32 + kq*8));
        f32x4 a = init ? f32x4{0.f,0.f,0.f,0.f} : acc[tr];
#pragma unroll
        for (int kk = 0; kk < 4; ++kk)
            a = __builtin_amdgcn_mfma_f32_16x16x32_bf16(af[kk], bf[kk], a, 0, 0, 0);
        acc[tr] = a;
    }
}

// epilogue: + bias, optional tanh, write bf16 swizzled act buffer
__device__ __forceinline__ void epi_act(const f32x4 acc[6], const float* __restrict__ bias,
                                        int tanh_mode, u16* dst, int lane, int ctile)
{
    const int c  = ctile*16 + (lane & 15);
    const int kq = lane >> 4;
    const float b = bias[c];
#pragma unroll
    for (int tr = 0; tr < 6; ++tr) {
#pragma unroll
        for (int q = 0; q < 4; ++q) {
            int r = tr*16 + kq*4 + q;
            float v = acc[tr][q] + b;
            if (tanh_mode) v = tanh_f(v);
            dst[r*128 + SWZ(r, c)] = f2bf(v);
        }
    }
}

// epilogue: + bias, write f32 (unswizzled) buffer
__device__ __forceinline__ void epi_f32(const f32x4 acc[6], const float* __restrict__ bias,
                                        float* dst, int lane, int ctile)
{
    const int c  = ctile*16 + (lane & 15);
    const int kq = lane >> 4;
    const float b = bias[c];
#pragma unroll
    for (int tr = 0; tr < 6; ++tr)
#pragma unroll
        for (int q = 0; q < 4; ++q) {
            int r = tr*16 + kq*4 + q;
            dst[r*128 + c] = acc[tr][q] + b;
        }
}

// copy one 32KB pre-swizzled weight image ws -> LDS (512 threads)
__device__ __forceinline__ void stageW(const u16* __restrict__ src, u16* dst, int tid){
    const uint4* s = reinterpret_cast<const uint4*>(src);
    uint4* d = reinterpret_cast<uint4*>(dst);
#pragma unroll
    for (int i = 0; i < 4; ++i) d[i*512 + tid] = s[i*512 + tid];
}

// LN + relu + 2-wide head GEMV + (optional elu) + store to loc_out
__device__ __forceinline__ void lnhead(const u16* src, const float* __restrict__ gv,
                                       const float* __restrict__ bv,
                                       const float* __restrict__ w2,
                                       const float* __restrict__ b2v,
                                       int off, int elu, int tt, int r0,
                                       float* __restrict__ outp, int tid)
{
    if (tid >= 4*RBLK) return;
    int row = tid >> 2, part = tid & 3;
    float v[32]; float s = 0.f, sq = 0.f;
#pragma unroll
    for (int u = 0; u < 4; ++u){
        int cb = part*32 + u*8;
        uint4 pk = *reinterpret_cast<const uint4*>(src + row*HD + SWZ(row, cb));
        float x0=bf2f(pk.x), x1=bf2f(pk.x>>16), x2=bf2f(pk.y), x3=bf2f(pk.y>>16);
        float x4=bf2f(pk.z), x5=bf2f(pk.z>>16), x6=bf2f(pk.w), x7=bf2f(pk.w>>16);
        v[u*8+0]=x0; v[u*8+1]=x1; v[u*8+2]=x2; v[u*8+3]=x3;
        v[u*8+4]=x4; v[u*8+5]=x5; v[u*8+6]=x6; v[u*8+7]=x7;
        s += x0+x1+x2+x3+x4+x5+x6+x7;
        sq += x0*x0+x1*x1+x2*x2+x3*x3+x4*x4+x5*x5+x6*x6+x7*x7;
    }
    s  += __shfl_xor(s, 1);  sq += __shfl_xor(sq, 1);
    s  += __shfl_xor(s, 2);  sq += __shfl_xor(sq, 2);
    float mu = s * (1.f/128.f);
    float rstd = rsqrtf(sq*(1.f/128.f) - mu*mu + LN_EPS);
    float a0 = 0.f, a1 = 0.f;
#pragma unroll
    for (int i = 0; i < 32; ++i){
        int cc = part*32 + i;
        float h = (v[i]-mu)*rstd*gv[cc] + bv[cc];
        h = fmaxf(h, 0.f);
        a0 += h * w2[cc*2]; a1 += h * w2[cc*2+1];
    }
    a0 += __shfl_xor(a0,1); a1 += __shfl_xor(a1,1);
    a0 += __shfl_xor(a0,2); a1 += __shfl_xor(a1,2);
    if (part == 0){
        a0 += b2v[0]; a1 += b2v[1];
        if (elu){
            a0 = (a0 > 0.f ? a0 : __expf(a0)-1.f) + 1.001f;
            a1 = (a1 > 0.f ? a1 : __expf(a1)-1.f) + 1.001f;
        }
        size_t o = ((size_t)(r0+row)*TSTEPS + tt)*4 + off;
        outp[o] = a0; outp[o+1] = a1;
    }
}

// ---------- weight image prep: f32 -> bf16, transposed, swizzled ----------
__global__ void prep_w(const float* __restrict__ fw1, const float* __restrict__ fw2,
                       const float* __restrict__ fw3, const float* __restrict__ gw1,
                       const float* __restrict__ gw2, const float* __restrict__ dw1,
                       const float* __restrict__ sw1, const float* __restrict__ aw,
                       const float* __restrict__ pw1, u16* __restrict__ ws)
{
    int img = blockIdx.y;
    int idx = blockIdx.x * 256 + threadIdx.x;   // 0..16383
    int k = idx >> 7, j = idx & 127;
    const float* W = fw1; int sr = k;
    switch (img) {
        case 0: W = fw1; break;  case 1: W = fw2; break;  case 2: W = fw3; break;
        case 3: W = gw1; break;  case 4: W = gw2; break;
        case 5: W = dw1; break;  case 6: W = sw1; break;
        case 7: W = aw;  break;  case 8: W = aw;  sr = k + 128; break;
        case 9: W = pw1; break;  case 10: W = pw1; sr = k + 128; break;
    }
    ws[(size_t)img*16384 + j*128 + SWZ(j, k)] = f2bf(W[(size_t)sr*128 + j]);
}

// ---------- the fused persistent kernel ----------
__global__ __launch_bounds__(512, 2) void sde_fused(
    const float* __restrict__ lE, const float* __restrict__ gE,
    const float* __restrict__ noise,
    const float* __restrict__ aggr_b, const float* __restrict__ aggr_g, const float* __restrict__ aggr_be,
    const float* __restrict__ fw1, const float* __restrict__ fb1,
    const float* __restrict__ fb2, const float* __restrict__ fb3,
    const float* __restrict__ gw1, const float* __restrict__ gb1,
    const float* __restrict__ gb2, const float* __restrict__ gw3, const float* __restrict__ gb3,
    const float* __restrict__ db1, const float* __restrict__ dg, const float* __restrict__ dbe,
    const float* __restrict__ dw2, const float* __restrict__ db2,
    const float* __restrict__ sb1, const float* __restrict__ sg, const float* __restrict__ sbe,
    const float* __restrict__ sw2, const float* __restrict__ sb2,
    const float* __restrict__ pb1, const float* __restrict__ pg, const float* __restrict__ pbe,
    const float* __restrict__ pw2, const float* __restrict__ pb2,
    const unsigned char* __restrict__ pmask,
    const u16* __restrict__ wimg,
    float* __restrict__ outp)
{
    __shared__ float Yf[RBLK*HD];            // f32 state (48 KB)
    __shared__ u16  act[3][RBLK*HD];         // bf16 activations, swizzled (72 KB)
    __shared__ u16  wbuf[HD*HD];             // weight tile (32 KB)
    __shared__ float sbias[2*HD];
    __shared__ float grow[RBLK];

    const int tid  = threadIdx.x;
    const int lane = tid & 63;
    const int wid  = tid >> 6;
    const int r0   = blockIdx.x * RBLK;

    const u16* wF1 = wimg;
    const u16* wF2 = wimg + 1*16384;
    const u16* wF3 = wimg + 2*16384;
    const u16* wG1 = wimg + 3*16384;
    const u16* wG2 = wimg + 4*16384;
    const u16* wD1 = wimg + 5*16384;
    const u16* wS1 = wimg + 6*16384;
    const u16* wA0 = wimg + 7*16384;
    const u16* wA1 = wimg + 8*16384;
    const u16* wP0 = wimg + 9*16384;
    const u16* wP1 = wimg + 10*16384;

    u16* Xc = &act[0][0];   // [96][256] concat staging aliases act[0..1]

    // -------- prologue: stage Xc = [global_embed | local_embed] bf16 swizzled --------
#pragma unroll
    for (int i = 0; i < 6; ++i) {
        int gidx = i*512 + tid;             // 0..3071
        int r = gidx >> 5;
        int k = (gidx & 31) * 8;
        int gr = r0 + r;
        const float* src = (k < HD) ? (gE + (size_t)gr*HD + k)
                                    : (lE + (size_t)(gr & (Adim-1))*HD + (k - HD));
        float4 v0 = reinterpret_cast<const float4*>(src)[0];
        float4 v1 = reinterpret_cast<const float4*>(src)[1];
        uint4 pk = { pack2(v0.x, v0.y), pack2(v0.z, v0.w),
                     pack2(v1.x, v1.y), pack2(v1.z, v1.w) };
        *reinterpret_cast<uint4*>(Xc + r*256 + SWZ(r, k)) = pk;
    }
    __syncthreads();

    f32x4 acc[6];

    // -------- pi head: pin = [le|ge] @ p_w1 == Xc(ge)@P[128:] + Xc(le)@P[:128] --------
    stageW(wP1, wbuf, tid);  __syncthreads();
    gemm6(Xc, 256, 0, wbuf, lane, wid, acc, true);
    __syncthreads();
    stageW(wP0, wbuf, tid);  __syncthreads();
    gemm6(Xc, 256, 128, wbuf, lane, wid, acc, false);
    epi_f32(acc, pb1, Yf, lane, wid);
    __syncthreads();

    if (tid < 4*RBLK) {
        int row = tid >> 2, part = tid & 3;
        const float* yr = Yf + row*HD + part*32;
        float v[32]; float s = 0.f, sq = 0.f;
#pragma unroll
        for (int i = 0; i < 32; ++i){ float x = yr[i]; v[i] = x; s += x; sq += x*x; }
        s += __shfl_xor(s,1); sq += __shfl_xor(sq,1);
        s += __shfl_xor(s,2); sq += __shfl_xor(sq,2);
        float mu = s*(1.f/128.f);
        float rstd = rsqrtf(sq*(1.f/128.f) - mu*mu + LN_EPS);
        float a0 = 0.f;
#pragma unroll
        for (int i = 0; i < 32; ++i){
            int cc = part*32 + i;
            float h = (v[i]-mu)*rstd*pg[cc] + pbe[cc];
            a0 += fmaxf(h, 0.f) * pw2[cc];
        }
        a0 += __shfl_xor(a0,1); a0 += __shfl_xor(a0,2);
        if (part == 0) {
            int gr = r0 + row;
            outp[PI_OFF + (size_t)(gr & (Adim-1))*Mdim + (gr >> 12)] = a0 + pb2[0];
        }
    }
    if (tid < RBLK) {              // reg_mask (only m==0 rows map to unique a)
        int gr = r0 + tid;
        if (gr < Adim) {
            const unsigned char* pm = pmask + (size_t)gr*50 + 20;
            float* o = outp + MASK_OFF + (size_t)gr*TSTEPS;
#pragma unroll
            for (int i = 0; i < TSTEPS; ++i) o[i] = pm[i] ? 0.f : 1.f;
        }
    }
    __syncthreads();

    // -------- aggr head -> h0 --------
    stageW(wA0, wbuf, tid);  __syncthreads();
    gemm6(Xc, 256, 0, wbuf, lane, wid, acc, true);
    __syncthreads();
    stageW(wA1, wbuf, tid);  __syncthreads();
    gemm6(Xc, 256, 128, wbuf, lane, wid, acc, false);
    epi_f32(acc, aggr_b, Yf, lane, wid);
    __syncthreads();
    if (tid < 4*RBLK) {            // LN + relu -> Yf (f32 state) + act[0] (bf16)
        int row = tid >> 2, part = tid & 3;
        float* yr = Yf + row*HD + part*32;
        float v[32]; float s = 0.f, sq = 0.f;
#pragma unroll
        for (int i = 0; i < 32; ++i){ float x = yr[i]; v[i] = x; s += x; sq += x*x; }
        s += __shfl_xor(s,1); sq += __shfl_xor(sq,1);
        s += __shfl_xor(s,2); sq += __shfl_xor(sq,2);
        float mu = s*(1.f/128.f);
        float rstd = rsqrtf(sq*(1.f/128.f) - mu*mu + LN_EPS);
#pragma unroll
        for (int i = 0; i < 32; ++i){
            int cc = part*32 + i;
            float h = (v[i]-mu)*rstd*aggr_g[cc] + aggr_be[cc];
            h = fmaxf(h, 0.f);
            v[i] = h; yr[i] = h;
        }
#pragma unroll
        for (int u = 0; u < 4; ++u){
            uint4 pk = { pack2(v[u*8+0],v[u*8+1]), pack2(v[u*8+2],v[u*8+3]),
                         pack2(v[u*8+4],v[u*8+5]), pack2(v[u*8+6],v[u*8+7]) };
            *reinterpret_cast<uint4*>(&act[0][row*HD + SWZ(row, part*32+u*8)]) = pk;
        }
    }
    __syncthreads();

    // -------- Euler-Maruyama scan, fully block-local --------
    int xi = 0, zi = 2;            // state buffer / second scratch; act[1] fixed scratch
    for (int tt = 0; tt < TSTEPS; ++tt) {
        float t = tt * DT_C;
        // L1f (+ per-step folded time bias)
        stageW(wF1, wbuf, tid);
        if (tid < 128) {
            float st = sinf(t), ct = cosf(t);
            sbias[tid] = fb1[tid] + st * fw1[128*HD + tid] + ct * fw1[129*HD + tid];
        } else if (tid < 256) {
            int c = tid - 128;
            float st = sinf(t), ct = cosf(t);
            sbias[128+c] = gb1[c] + st * gw1[128*HD + c] + ct * gw1[129*HD + c];
        }
        __syncthreads();
        gemm6(&act[xi][0], 128, 0, wbuf, lane, wid, acc, true);
        epi_act(acc, sbias, 1, &act[1][0], lane, wid);
        __syncthreads();
        // L1g
        stageW(wG1, wbuf, tid);  __syncthreads();
        gemm6(&act[xi][0], 128, 0, wbuf, lane, wid, acc, true);
        epi_act(acc, sbias+128, 1, &act[zi][0], lane, wid);
        __syncthreads();
        // L2f: act1(h1f) -> act[xi] (h2f)
        stageW(wF2, wbuf, tid);  __syncthreads();
        gemm6(&act[1][0], 128, 0, wbuf, lane, wid, acc, true);
        epi_act(acc, fb2, 1, &act[xi][0], lane, wid);
        __syncthreads();
        // L2g: act[zi](h1g) -> act[1] (h2g)
        stageW(wG2, wbuf, tid);  __syncthreads();
        gemm6(&act[zi][0], 128, 0, wbuf, lane, wid, acc, true);
        epi_act(acc, gb2, 1, &act[1][0], lane, wid);
        __syncthreads();
        // diffusion scalar g = sigmoid(h2g . g_w3 + b); stage F3 concurrently
        stageW(wF3, wbuf, tid);
        if (tid < 4*RBLK) {
            int row = tid>>2, part = tid&3;
            float s = 0.f;
#pragma unroll
            for (int u = 0; u < 4; ++u){
                int cb = part*32 + u*8;
                uint4 pk = *reinterpret_cast<const uint4*>(&act[1][row*HD + SWZ(row, cb)]);
                s += bf2f(pk.x)*gw3[cb+0]   + bf2f(pk.x>>16)*gw3[cb+1]
                   + bf2f(pk.y)*gw3[cb+2]   + bf2f(pk.y>>16)*gw3[cb+3]
                   + bf2f(pk.z)*gw3[cb+4]   + bf2f(pk.z>>16)*gw3[cb+5]
                   + bf2f(pk.w)*gw3[cb+6]   + bf2f(pk.w>>16)*gw3[cb+7];
            }
            s += __shfl_xor(s,1); s += __shfl_xor(s,2);
            if (part == 0) grow[row] = sigm_f(s + gb3[0]);
        }
        __syncthreads();
        // L3f + Euler update: drift from act[xi](h2f); new state -> Yf + act[zi]
        gemm6(&act[xi][0], 128, 0, wbuf, lane, wid, acc, true);
        {
            const int c  = wid*16 + (lane & 15);
            const int kq = lane >> 4;
            const float b3 = fb3[c];
#pragma unroll
            for (int tr = 0; tr < 6; ++tr)
#pragma unroll
                for (int q = 0; q < 4; ++q) {
                    int r = tr*16 + kq*4 + q;
                    int gr = r0 + r;
                    float z = noise[((size_t)tt*NROWS + gr)*HD + c];
                    float y = Yf[r*HD + c] + (acc[tr][q] + b3)*DT_C + grow[r]*SQDT_C*z;
                    Yf[r*HD + c] = y;
                    act[zi][r*128 + SWZ(r, c)] = f2bf(y);
                }
        }
        __syncthreads();
        // decoder loc head
        stageW(wD1, wbuf, tid);  __syncthreads();
        gemm6(&act[zi][0], 128, 0, wbuf, lane, wid, acc, true);
        epi_act(acc, db1, 0, &act[1][0], lane, wid);
        __syncthreads();
        lnhead(&act[1][0], dg, dbe, dw2, db2, 0, 0, tt, r0, outp, tid);
        stageW(wS1, wbuf, tid);
        __syncthreads();
        // scale head
        gemm6(&act[zi][0], 128, 0, wbuf, lane, wid, acc, true);
        epi_act(acc, sb1, 0, &act[1][0], lane, wid);
        __syncthreads();
        lnhead(&act[1][0], sg, sbe, sw2, sb2, 2, 1, tt, r0, outp, tid);
        __syncthreads();
        // swap state buffer
        int tmpi = xi; xi = zi; zi = tmpi;
    }
}

extern "C" void kernel_launch(void* const* d_in, const int* in_sizes, int n_in,
                              void* d_out, int out_size, void* d_ws, size_t ws_size,
                              hipStream_t stream) {
    const float* lE      = (const float*)d_in[0];
    const float* gE      = (const float*)d_in[1];
    const float* noise   = (const float*)d_in[2];
    const float* aggr_w  = (const float*)d_in[3];
    const float* aggr_b  = (const float*)d_in[4];
    const float* aggr_g  = (const float*)d_in[5];
    const float* aggr_be = (const float*)d_in[6];
    const float* fw1 = (const float*)d_in[7];
    const float* fb1 = (const float*)d_in[8];
    const float* fw2 = (const float*)d_in[9];
    const float* fb2 = (const float*)d_in[10];
    const float* fw3 = (const float*)d_in[11];
    const float* fb3 = (const float*)d_in[12];
    const float* gw1 = (const float*)d_in[13];
    const float* gb1 = (const float*)d_in[14];
    const float* gw2 = (const float*)d_in[15];
    const float* gb2 = (const float*)d_in[16];
    const float* gw3 = (const float*)d_in[17];
    const float* gb3 = (const float*)d_in[18];
    const float* dw1 = (const float*)d_in[19];
    const float* db1 = (const float*)d_in[20];
    const float* dg  = (const float*)d_in[21];
    const float* dbe = (const float*)d_in[22];
    const float* dw2 = (const float*)d_in[23];
    const float* db2 = (const float*)d_in[24];
    const float* sw1 = (const float*)d_in[25];
    const float* sb1 = (const float*)d_in[26];
    const float* sg  = (const float*)d_in[27];
    const float* sbe = (const float*)d_in[28];
    const float* sw2 = (const float*)d_in[29];
    const float* sb2 = (const float*)d_in[30];
    const float* pw1 = (const float*)d_in[31];
    const float* pb1 = (const float*)d_in[32];
    const float* pg  = (const float*)d_in[33];
    const float* pbe = (const float*)d_in[34];
    const float* pw2 = (const float*)d_in[35];
    const float* pb2 = (const float*)d_in[36];
    const unsigned char* pmask = (const unsigned char*)d_in[37];
    float* outp = (float*)d_out;
    u16* wimg = (u16*)d_ws;   // 11 images x 16384 u16 = 704 KB

    prep_w<<<dim3(64, 11), 256, 0, stream>>>(fw1, fw2, fw3, gw1, gw2, dw1, sw1,
                                             aggr_w, pw1, wimg);
    sde_fused<<<NBLKS, 512, 0, stream>>>(
        lE, gE, noise, aggr_b, aggr_g, aggr_be,
        fw1, fb1, fb2, fb3,
        gw1, gb1, gb2, gw3, gb3,
        db1, dg, dbe, dw2, db2,
        sb1, sg, sbe, sw2, sb2,
        pb1, pg, pbe, pw2, pb2,
        pmask, wimg, outp);
}

// Round 2
// 1047.416 us; speedup vs baseline: 1.5658x; 1.5658x over previous
//
#include <hip/hip_runtime.h>

#define Adim 4096
#define Mdim 6
#define HD 128
#define TSTEPS 30
#define NROWS 24576
#define RBLK 96
#define NBLKS 256           // NROWS / RBLK
#define DT_C 0.2f
#define SQDT_C 0.44721359549995794f
#define LN_EPS 1e-5f

#define PI_OFF   2949120    // 6*4096*30*4
#define MASK_OFF 2973696    // PI_OFF + 24576

typedef unsigned short u16;
typedef __bf16 bf16x8 __attribute__((ext_vector_type(8)));
typedef float f32x4 __attribute__((ext_vector_type(4)));

__device__ __forceinline__ u16 f2bf(float x){
    unsigned u = __builtin_bit_cast(unsigned, x);
    u = (u + 0x7fffu + ((u >> 16) & 1u)) >> 16;
    return (u16)u;
}
__device__ __forceinline__ float bf2f(unsigned h){
    unsigned u = (h & 0xffffu) << 16;
    return __builtin_bit_cast(float, u);
}
__device__ __forceinline__ unsigned pack2(float a, float b){
    return (unsigned)f2bf(a) | ((unsigned)f2bf(b) << 16);
}
__device__ __forceinline__ float tanh_f(float x){
    return 1.0f - 2.0f / (1.0f + __expf(2.0f * x));
}
__device__ __forceinline__ float sigm_f(float x){
    return 1.0f / (1.0f + __expf(-x));
}
// XOR swizzle in u16 units within a row (conflict-free ds_read_b128)
#define SWZ(r,k) ((k) ^ (((r)&7)<<3))

// ---- load this lane's weight a-frags (16 output channels per wave) ----
__device__ __forceinline__ void loadW(const u16* __restrict__ img, int lane, int wid,
                                      bf16x8 W[4]) {
    const int c = wid*16 + (lane & 15);
    const int kq = lane >> 4;
#pragma unroll
    for (int kk = 0; kk < 4; ++kk)
        W[kk] = *reinterpret_cast<const bf16x8*>(img + c*HD + SWZ(c, kk*32 + kq*8));
}

// ---- GEMM (swapped operands): D[c][r] = sum_k W[c][k] act[r][k] ----
__device__ __forceinline__ void gemm1(const u16* __restrict__ act, const bf16x8 (&W)[4],
                                      int lane, f32x4 acc[6]) {
    const int rl = lane & 15, kq = lane >> 4;
#pragma unroll
    for (int tr = 0; tr < 6; ++tr) {
        const int r = tr*16 + rl;
        const u16* arow = act + r*HD;
        f32x4 a = {0.f,0.f,0.f,0.f};
#pragma unroll
        for (int kk = 0; kk < 4; ++kk) {
            bf16x8 bf = *reinterpret_cast<const bf16x8*>(arow + SWZ(r, kk*32 + kq*8));
            a = __builtin_amdgcn_mfma_f32_16x16x32_bf16(W[kk], bf, a, 0, 0, 0);
        }
        acc[tr] = a;
    }
}
// dual-output: two weight sets share one activation read pass
__device__ __forceinline__ void gemm2(const u16* __restrict__ act,
                                      const bf16x8 (&Wx)[4], const bf16x8 (&Wy)[4],
                                      int lane, f32x4 accX[6], f32x4 accY[6]) {
    const int rl = lane & 15, kq = lane >> 4;
#pragma unroll
    for (int tr = 0; tr < 6; ++tr) {
        const int r = tr*16 + rl;
        const u16* arow = act + r*HD;
        f32x4 ax = {0.f,0.f,0.f,0.f}, ay = {0.f,0.f,0.f,0.f};
#pragma unroll
        for (int kk = 0; kk < 4; ++kk) {
            bf16x8 bf = *reinterpret_cast<const bf16x8*>(arow + SWZ(r, kk*32 + kq*8));
            ax = __builtin_amdgcn_mfma_f32_16x16x32_bf16(Wx[kk], bf, ax, 0, 0, 0);
            ay = __builtin_amdgcn_mfma_f32_16x16x32_bf16(Wy[kk], bf, ay, 0, 0, 0);
        }
        accX[tr] = ax; accY[tr] = ay;
    }
}

// ---- epilogues: lane holds rows r, 4 consecutive channels c0..c0+3 ----
__device__ __forceinline__ void epiT(const f32x4 acc[6], const float b[4],
                                     u16* dst, int lane, int wid) {
    const int c0 = wid*16 + ((lane>>4)<<2);
    const int rl = lane & 15;
#pragma unroll
    for (int tr = 0; tr < 6; ++tr) {
        int r = tr*16 + rl;
        float v0 = tanh_f(acc[tr][0] + b[0]);
        float v1 = tanh_f(acc[tr][1] + b[1]);
        float v2 = tanh_f(acc[tr][2] + b[2]);
        float v3 = tanh_f(acc[tr][3] + b[3]);
        uint2 pk = { pack2(v0, v1), pack2(v2, v3) };
        *reinterpret_cast<uint2*>(dst + r*HD + SWZ(r, c0)) = pk;
    }
}
__device__ __forceinline__ void epiN(const f32x4 acc[6], const float b[4],
                                     u16* dst, int lane, int wid) {
    const int c0 = wid*16 + ((lane>>4)<<2);
    const int rl = lane & 15;
#pragma unroll
    for (int tr = 0; tr < 6; ++tr) {
        int r = tr*16 + rl;
        uint2 pk = { pack2(acc[tr][0]+b[0], acc[tr][1]+b[1]),
                     pack2(acc[tr][2]+b[2], acc[tr][3]+b[3]) };
        *reinterpret_cast<uint2*>(dst + r*HD + SWZ(r, c0)) = pk;
    }
}
__device__ __forceinline__ void epiF(const f32x4 acc[6], const float* __restrict__ bias,
                                     float* dst, int lane, int wid) {
    const int c0 = wid*16 + ((lane>>4)<<2);
    const int rl = lane & 15;
    float4 b4 = *reinterpret_cast<const float4*>(bias + c0);
#pragma unroll
    for (int tr = 0; tr < 6; ++tr) {
        int r = tr*16 + rl;
        float4 v = { acc[tr][0]+b4.x, acc[tr][1]+b4.y, acc[tr][2]+b4.z, acc[tr][3]+b4.w };
        *reinterpret_cast<float4*>(dst + r*HD + c0) = v;
    }
}

// ---- prologue GEMM over Xc (lda=256, K accumulated in halves) ----
__device__ __forceinline__ void gemmX(const u16* __restrict__ Xc, int kBase,
                                      const u16* __restrict__ img,
                                      int lane, int wid, f32x4 acc[6], bool init) {
    bf16x8 W[4]; loadW(img, lane, wid, W);
    const int rl = lane & 15, kq = lane >> 4;
#pragma unroll
    for (int tr = 0; tr < 6; ++tr) {
        const int r = tr*16 + rl;
        const u16* arow = Xc + r*256;
        f32x4 a = init ? f32x4{0.f,0.f,0.f,0.f} : acc[tr];
#pragma unroll
        for (int kk = 0; kk < 4; ++kk) {
            bf16x8 bf = *reinterpret_cast<const bf16x8*>(arow + SWZ(r, kBase + kk*32 + kq*8));
            a = __builtin_amdgcn_mfma_f32_16x16x32_bf16(W[kk], bf, a, 0, 0, 0);
        }
        acc[tr] = a;
    }
}

// LN + relu + 2-wide head GEMV + (optional elu) + store to loc_out
__device__ __forceinline__ void lnhead(const u16* src, const float* __restrict__ gv,
                                       const float* __restrict__ bv,
                                       const float* __restrict__ w2,
                                       const float* __restrict__ b2v,
                                       int off, int elu, int tt, int r0,
                                       float* __restrict__ outp, int tid)
{
    if (tid >= 4*RBLK) return;
    int row = tid >> 2, part = tid & 3;
    float v[32]; float s = 0.f, sq = 0.f;
#pragma unroll
    for (int u = 0; u < 4; ++u){
        int cb = part*32 + u*8;
        uint4 pk = *reinterpret_cast<const uint4*>(src + row*HD + SWZ(row, cb));
        float x0=bf2f(pk.x), x1=bf2f(pk.x>>16), x2=bf2f(pk.y), x3=bf2f(pk.y>>16);
        float x4=bf2f(pk.z), x5=bf2f(pk.z>>16), x6=bf2f(pk.w), x7=bf2f(pk.w>>16);
        v[u*8+0]=x0; v[u*8+1]=x1; v[u*8+2]=x2; v[u*8+3]=x3;
        v[u*8+4]=x4; v[u*8+5]=x5; v[u*8+6]=x6; v[u*8+7]=x7;
        s += x0+x1+x2+x3+x4+x5+x6+x7;
        sq += x0*x0+x1*x1+x2*x2+x3*x3+x4*x4+x5*x5+x6*x6+x7*x7;
    }
    s  += __shfl_xor(s, 1);  sq += __shfl_xor(sq, 1);
    s  += __shfl_xor(s, 2);  sq += __shfl_xor(sq, 2);
    float mu = s * (1.f/128.f);
    float rstd = rsqrtf(sq*(1.f/128.f) - mu*mu + LN_EPS);
    float a0 = 0.f, a1 = 0.f;
#pragma unroll
    for (int i = 0; i < 32; ++i){
        int cc = part*32 + i;
        float h = (v[i]-mu)*rstd*gv[cc] + bv[cc];
        h = fmaxf(h, 0.f);
        a0 += h * w2[cc*2]; a1 += h * w2[cc*2+1];
    }
    a0 += __shfl_xor(a0,1); a1 += __shfl_xor(a1,1);
    a0 += __shfl_xor(a0,2); a1 += __shfl_xor(a1,2);
    if (part == 0){
        a0 += b2v[0]; a1 += b2v[1];
        if (elu){
            a0 = (a0 > 0.f ? a0 : __expf(a0)-1.f) + 1.001f;
            a1 = (a1 > 0.f ? a1 : __expf(a1)-1.f) + 1.001f;
        }
        size_t o = ((size_t)(r0+row)*TSTEPS + tt)*4 + off;
        outp[o] = a0; outp[o+1] = a1;
    }
}

// ---------- weight image prep: f32 -> bf16, transposed, swizzled ----------
__global__ void prep_w(const float* __restrict__ fw1, const float* __restrict__ fw2,
                       const float* __restrict__ fw3, const float* __restrict__ gw1,
                       const float* __restrict__ gw2, const float* __restrict__ dw1,
                       const float* __restrict__ sw1, const float* __restrict__ aw,
                       const float* __restrict__ pw1, u16* __restrict__ ws)
{
    int img = blockIdx.y;
    int idx = blockIdx.x * 256 + threadIdx.x;   // 0..16383
    int k = idx >> 7, j = idx & 127;
    const float* W = fw1; int sr = k;
    switch (img) {
        case 0: W = fw1; break;  case 1: W = fw2; break;  case 2: W = fw3; break;
        case 3: W = gw1; break;  case 4: W = gw2; break;
        case 5: W = dw1; break;  case 6: W = sw1; break;
        case 7: W = aw;  break;  case 8: W = aw;  sr = k + 128; break;
        case 9: W = pw1; break;  case 10: W = pw1; sr = k + 128; break;
    }
    ws[(size_t)img*16384 + j*128 + SWZ(j, k)] = f2bf(W[(size_t)sr*128 + j]);
}

// ---------- the fused persistent kernel ----------
__global__ __launch_bounds__(512, 1) void sde_fused(
    const float* __restrict__ lE, const float* __restrict__ gE,
    const float* __restrict__ noise,
    const float* __restrict__ aggr_b, const float* __restrict__ aggr_g, const float* __restrict__ aggr_be,
    const float* __restrict__ fw1, const float* __restrict__ fb1,
    const float* __restrict__ fb2, const float* __restrict__ fb3,
    const float* __restrict__ gw1, const float* __restrict__ gb1,
    const float* __restrict__ gb2, const float* __restrict__ gw3, const float* __restrict__ gb3,
    const float* __restrict__ db1, const float* __restrict__ dg, const float* __restrict__ dbe,
    const float* __restrict__ dw2, const float* __restrict__ db2,
    const float* __restrict__ sb1, const float* __restrict__ sg, const float* __restrict__ sbe,
    const float* __restrict__ sw2, const float* __restrict__ sb2,
    const float* __restrict__ pb1, const float* __restrict__ pg, const float* __restrict__ pbe,
    const float* __restrict__ pw2, const float* __restrict__ pb2,
    const unsigned char* __restrict__ pmask,
    const u16* __restrict__ wimg,
    float* __restrict__ outp)
{
    // LDS layout (flat, aliased between prologue and loop):
    //   loop:     Yf f32 @0 (48K) | Sb @48K | Ab @72K | Bb @96K | Cb @120K (24K each) | grow @144K
    //   prologue: Xc [96][256] bf16 @0 (48K) | preLN f32 @72K (48K, over Ab+Bb)
    __shared__ __align__(16) unsigned char SMEM[147840];
    float* Yf   = (float*)SMEM;
    u16*  Sb    = (u16*)(SMEM + 49152);
    u16*  Ab    = (u16*)(SMEM + 73728);
    u16*  Bb    = (u16*)(SMEM + 98304);
    u16*  Cb    = (u16*)(SMEM + 122880);
    float* grow = (float*)(SMEM + 147456);
    u16*  Xc    = (u16*)SMEM;
    float* preLN = (float*)(SMEM + 73728);

    const int tid  = threadIdx.x;
    const int lane = tid & 63;
    const int wid  = tid >> 6;
    const int r0   = blockIdx.x * RBLK;
    const int c0   = wid*16 + ((lane>>4)<<2);   // this lane's 4 output channels

    // -------- prologue: stage Xc = [global_embed | local_embed] bf16 swizzled --------
#pragma unroll
    for (int i = 0; i < 6; ++i) {
        int gidx = i*512 + tid;             // 0..3071
        int r = gidx >> 5;
        int k = (gidx & 31) * 8;
        int gr = r0 + r;
        const float* src = (k < HD) ? (gE + (size_t)gr*HD + k)
                                    : (lE + (size_t)(gr & (Adim-1))*HD + (k - HD));
        float4 v0 = reinterpret_cast<const float4*>(src)[0];
        float4 v1 = reinterpret_cast<const float4*>(src)[1];
        uint4 pk = { pack2(v0.x, v0.y), pack2(v0.z, v0.w),
                     pack2(v1.x, v1.y), pack2(v1.z, v1.w) };
        *reinterpret_cast<uint4*>(Xc + r*256 + SWZ(r, k)) = pk;
    }
    __syncthreads();

    f32x4 acc[6];

    // -------- pi head --------
    gemmX(Xc, 0,   wimg + 10*16384, lane, wid, acc, true);   // ge part
    gemmX(Xc, 128, wimg + 9*16384,  lane, wid, acc, false);  // le part
    epiF(acc, pb1, preLN, lane, wid);
    __syncthreads();

    if (tid < 4*RBLK) {
        int row = tid >> 2, part = tid & 3;
        const float* yr = preLN + row*HD + part*32;
        float v[32]; float s = 0.f, sq = 0.f;
#pragma unroll
        for (int i = 0; i < 32; ++i){ float x = yr[i]; v[i] = x; s += x; sq += x*x; }
        s += __shfl_xor(s,1); sq += __shfl_xor(sq,1);
        s += __shfl_xor(s,2); sq += __shfl_xor(sq,2);
        float mu = s*(1.f/128.f);
        float rstd = rsqrtf(sq*(1.f/128.f) - mu*mu + LN_EPS);
        float a0 = 0.f;
#pragma unroll
        for (int i = 0; i < 32; ++i){
            int cc = part*32 + i;
            float h = (v[i]-mu)*rstd*pg[cc] + pbe[cc];
            a0 += fmaxf(h, 0.f) * pw2[cc];
        }
        a0 += __shfl_xor(a0,1); a0 += __shfl_xor(a0,2);
        if (part == 0) {
            int gr = r0 + row;
            outp[PI_OFF + (size_t)(gr & (Adim-1))*Mdim + (gr >> 12)] = a0 + pb2[0];
        }
    }
    if (tid < RBLK) {              // reg_mask
        int gr = r0 + tid;
        if (gr < Adim) {
            const unsigned char* pm = pmask + (size_t)gr*50 + 20;
            float* o = outp + MASK_OFF + (size_t)gr*TSTEPS;
#pragma unroll
            for (int i = 0; i < TSTEPS; ++i) o[i] = pm[i] ? 0.f : 1.f;
        }
    }
    __syncthreads();

    // -------- aggr head -> h0 --------
    gemmX(Xc, 0,   wimg + 7*16384, lane, wid, acc, true);
    gemmX(Xc, 128, wimg + 8*16384, lane, wid, acc, false);
    epiF(acc, aggr_b, preLN, lane, wid);
    __syncthreads();
    if (tid < 4*RBLK) {            // LN + relu -> Yf (f32 state) + Sb (bf16)
        int row = tid >> 2, part = tid & 3;
        const float* yr = preLN + row*HD + part*32;
        float v[32]; float s = 0.f, sq = 0.f;
#pragma unroll
        for (int i = 0; i < 32; ++i){ float x = yr[i]; v[i] = x; s += x; sq += x*x; }
        s += __shfl_xor(s,1); sq += __shfl_xor(sq,1);
        s += __shfl_xor(s,2); sq += __shfl_xor(sq,2);
        float mu = s*(1.f/128.f);
        float rstd = rsqrtf(sq*(1.f/128.f) - mu*mu + LN_EPS);
#pragma unroll
        for (int i = 0; i < 32; ++i){
            int cc = part*32 + i;
            float h = (v[i]-mu)*rstd*aggr_g[cc] + aggr_be[cc];
            v[i] = fmaxf(h, 0.f);
        }
#pragma unroll
        for (int i = 0; i < 32; ++i) Yf[row*HD + part*32 + i] = v[i];
#pragma unroll
        for (int u = 0; u < 4; ++u){
            uint4 pk = { pack2(v[u*8+0],v[u*8+1]), pack2(v[u*8+2],v[u*8+3]),
                         pack2(v[u*8+4],v[u*8+5]), pack2(v[u*8+6],v[u*8+7]) };
            *reinterpret_cast<uint4*>(&Sb[row*HD + SWZ(row, part*32+u*8)]) = pk;
        }
    }
    __syncthreads();

    // -------- loop weights into registers (112 VGPR) --------
    bf16x8 WF1[4], WG1[4], WF2[4], WG2[4], WF3[4], WD1[4], WS1[4];
    loadW(wimg + 0*16384, lane, wid, WF1);
    loadW(wimg + 3*16384, lane, wid, WG1);
    loadW(wimg + 1*16384, lane, wid, WF2);
    loadW(wimg + 4*16384, lane, wid, WG2);
    loadW(wimg + 2*16384, lane, wid, WF3);
    loadW(wimg + 5*16384, lane, wid, WD1);
    loadW(wimg + 6*16384, lane, wid, WS1);

    // per-lane loop-invariant biases / time-bias coefficients
    float fb2c[4], gb2c[4], fb3c[4], db1c[4], sb1c[4];
    float fb1c[4], gb1c[4], fw1s[4], fw1cc[4], gw1s[4], gw1cc[4];
#pragma unroll
    for (int q = 0; q < 4; ++q) {
        int c = c0 + q;
        fb2c[q]=fb2[c]; gb2c[q]=gb2[c]; fb3c[q]=fb3[c]; db1c[q]=db1[c]; sb1c[q]=sb1[c];
        fb1c[q]=fb1[c]; gb1c[q]=gb1[c];
        fw1s[q]=fw1[128*HD+c]; fw1cc[q]=fw1[129*HD+c];
        gw1s[q]=gw1[128*HD+c]; gw1cc[q]=gw1[129*HD+c];
    }

    // -------- Euler-Maruyama scan --------
    for (int tt = 0; tt < TSTEPS; ++tt) {
        float t = tt * DT_C;
        float st = __sinf(t), ct = __cosf(t);
        float bF[4], bG[4];
#pragma unroll
        for (int q = 0; q < 4; ++q) {
            bF[q] = fb1c[q] + st*fw1s[q] + ct*fw1cc[q];
            bG[q] = gb1c[q] + st*gw1s[q] + ct*gw1cc[q];
        }
        // P1: L1f,L1g (shared input Sb)
        {
            f32x4 aF[6], aG[6];
            gemm2(Sb, WF1, WG1, lane, aF, aG);
            epiT(aF, bF, Ab, lane, wid);
            epiT(aG, bG, Bb, lane, wid);
        }
        __syncthreads();
        // P2: noise prefetch (update layout) + L2f(Ab->Cb), L2g(Bb->Sb)
        float4 nz[6];
        {
            const float* np = noise + ((size_t)tt*NROWS + r0)*HD;
#pragma unroll
            for (int p = 0; p < 6; ++p)
                nz[p] = *reinterpret_cast<const float4*>(np + (p*512 + tid)*4);
        }
        {
            f32x4 a1[6];
            gemm1(Ab, WF2, lane, a1);
            epiT(a1, fb2c, Cb, lane, wid);
            gemm1(Bb, WG2, lane, a1);
            epiT(a1, gb2c, Sb, lane, wid);
        }
        __syncthreads();
        // P3: L3f drift (Cb -> Bb, no tanh) + gw3 GEMV (Sb -> grow)
        {
            f32x4 a1[6];
            gemm1(Cb, WF3, lane, a1);
            epiN(a1, fb3c, Bb, lane, wid);
        }
        if (tid < 4*RBLK) {
            int row = tid >> 2, part = tid & 3;
            float s = 0.f;
#pragma unroll
            for (int u = 0; u < 4; ++u){
                int cb = part*32 + u*8;
                uint4 pk = *reinterpret_cast<const uint4*>(Sb + row*HD + SWZ(row, cb));
                s += bf2f(pk.x)*gw3[cb+0]   + bf2f(pk.x>>16)*gw3[cb+1]
                   + bf2f(pk.y)*gw3[cb+2]   + bf2f(pk.y>>16)*gw3[cb+3]
                   + bf2f(pk.z)*gw3[cb+4]   + bf2f(pk.z>>16)*gw3[cb+5]
                   + bf2f(pk.w)*gw3[cb+6]   + bf2f(pk.w>>16)*gw3[cb+7];
            }
            s += __shfl_xor(s,1); s += __shfl_xor(s,2);
            if (part == 0) grow[row] = sigm_f(s + gb3[0]);
        }
        __syncthreads();
        // P4: Euler update (linear layout, coalesced)
#pragma unroll
        for (int p = 0; p < 6; ++p) {
            int flat4 = p*512 + tid;
            int r  = flat4 >> 5;
            int k0 = (flat4 & 31) * 4;
            int sk = SWZ(r, k0);
            uint2 dpk = *reinterpret_cast<const uint2*>(Bb + r*HD + sk);
            float4 y = *reinterpret_cast<const float4*>(Yf + r*HD + k0);
            float g = grow[r] * SQDT_C;
            float4 z = nz[p];
            y.x += bf2f(dpk.x)     * DT_C + g*z.x;
            y.y += bf2f(dpk.x>>16) * DT_C + g*z.y;
            y.z += bf2f(dpk.y)     * DT_C + g*z.z;
            y.w += bf2f(dpk.y>>16) * DT_C + g*z.w;
            *reinterpret_cast<float4*>(Yf + r*HD + k0) = y;
            uint2 s2 = { pack2(y.x, y.y), pack2(y.z, y.w) };
            *reinterpret_cast<uint2*>(Sb + r*HD + sk) = s2;
        }
        __syncthreads();
        // P5: D1,S1 (shared input Sb)
        {
            f32x4 aD[6], aS[6];
            gemm2(Sb, WD1, WS1, lane, aD, aS);
            epiN(aD, db1c, Ab, lane, wid);
            epiN(aS, sb1c, Cb, lane, wid);
        }
        __syncthreads();
        // P6: ln + heads
        lnhead(Ab, dg, dbe, dw2, db2, 0, 0, tt, r0, outp, tid);
        lnhead(Cb, sg, sbe, sw2, sb2, 2, 1, tt, r0, outp, tid);
        __syncthreads();
    }
}

extern "C" void kernel_launch(void* const* d_in, const int* in_sizes, int n_in,
                              void* d_out, int out_size, void* d_ws, size_t ws_size,
                              hipStream_t stream) {
    const float* lE      = (const float*)d_in[0];
    const float* gE      = (const float*)d_in[1];
    const float* noise   = (const float*)d_in[2];
    const float* aggr_w  = (const float*)d_in[3];
    const float* aggr_b  = (const float*)d_in[4];
    const float* aggr_g  = (const float*)d_in[5];
    const float* aggr_be = (const float*)d_in[6];
    const float* fw1 = (const float*)d_in[7];
    const float* fb1 = (const float*)d_in[8];
    const float* fw2 = (const float*)d_in[9];
    const float* fb2 = (const float*)d_in[10];
    const float* fw3 = (const float*)d_in[11];
    const float* fb3 = (const float*)d_in[12];
    const float* gw1 = (const float*)d_in[13];
    const float* gb1 = (const float*)d_in[14];
    const float* gw2 = (const float*)d_in[15];
    const float* gb2 = (const float*)d_in[16];
    const float* gw3 = (const float*)d_in[17];
    const float* gb3 = (const float*)d_in[18];
    const float* dw1 = (const float*)d_in[19];
    const float* db1 = (const float*)d_in[20];
    const float* dg  = (const float*)d_in[21];
    const float* dbe = (const float*)d_in[22];
    const float* dw2 = (const float*)d_in[23];
    const float* db2 = (const float*)d_in[24];
    const float* sw1 = (const float*)d_in[25];
    const float* sb1 = (const float*)d_in[26];
    const float* sg  = (const float*)d_in[27];
    const float* sbe = (const float*)d_in[28];
    const float* sw2 = (const float*)d_in[29];
    const float* sb2 = (const float*)d_in[30];
    const float* pw1 = (const float*)d_in[31];
    const float* pb1 = (const float*)d_in[32];
    const float* pg  = (const float*)d_in[33];
    const float* pbe = (const float*)d_in[34];
    const float* pw2 = (const float*)d_in[35];
    const float* pb2 = (const float*)d_in[36];
    const unsigned char* pmask = (const unsigned char*)d_in[37];
    float* outp = (float*)d_out;
    u16* wimg = (u16*)d_ws;   // 11 images x 16384 u16 = 352 KB

    prep_w<<<dim3(64, 11), 256, 0, stream>>>(fw1, fw2, fw3, gw1, gw2, dw1, sw1,
                                             aggr_w, pw1, wimg);
    sde_fused<<<NBLKS, 512, 0, stream>>>(
        lE, gE, noise, aggr_b, aggr_g, aggr_be,
        fw1, fb1, fb2, fb3,
        gw1, gb1, gb2, gw3, gb3,
        db1, dg, dbe, dw2, db2,
        sb1, sg, sbe, sw2, sb2,
        pb1, pg, pbe, pw2, pb2,
        pmask, wimg, outp);
}

// Round 3
// 615.185 us; speedup vs baseline: 2.6660x; 1.7026x over previous
//
#include <hip/hip_runtime.h>

#define Adim 4096
#define HD 128
#define TSTEPS 30
#define NROWS 24576
#define RBLK 32
#define NBLKS 768           // NROWS / RBLK
#define DT_C 0.2f
#define SQDT_C 0.44721359549995794f
#define LN_EPS 1e-5f

#define PI_OFF   2949120    // 6*4096*30*4
#define MASK_OFF 2973696    // PI_OFF + 24576

typedef unsigned short u16;
typedef __bf16 bf16x8 __attribute__((ext_vector_type(8)));
typedef float f32x4 __attribute__((ext_vector_type(4)));

__device__ __forceinline__ u16 f2bf(float x){
    unsigned u = __builtin_bit_cast(unsigned, x);
    u = (u + 0x7fffu + ((u >> 16) & 1u)) >> 16;
    return (u16)u;
}
__device__ __forceinline__ float bf2f(unsigned h){
    unsigned u = (h & 0xffffu) << 16;
    return __builtin_bit_cast(float, u);
}
__device__ __forceinline__ unsigned pack2(float a, float b){
    return (unsigned)f2bf(a) | ((unsigned)f2bf(b) << 16);
}
__device__ __forceinline__ float tanh_f(float x){
    return 1.0f - 2.0f / (1.0f + __expf(2.0f * x));
}
__device__ __forceinline__ float sigm_f(float x){
    return 1.0f / (1.0f + __expf(-x));
}
#define SWZ(r,k) ((k) ^ (((r)&7)<<3))

// ---- per-wave weight fragments: 16 output channels per wave ----
__device__ __forceinline__ void loadW(const u16* __restrict__ img, int lane, int wid,
                                      bf16x8 W[4]) {
    const int c = wid*16 + (lane & 15);
    const int kq = lane >> 4;
#pragma unroll
    for (int kk = 0; kk < 4; ++kk)
        W[kk] = *reinterpret_cast<const bf16x8*>(img + c*HD + SWZ(c, kk*32 + kq*8));
}

// ---- GEMM (swapped): D[c][r] = sum_k W[c][k] act[r][k]; 32 rows = 2 tiles ----
__device__ __forceinline__ void gemm1(const u16* __restrict__ act, const bf16x8 (&W)[4],
                                      int lane, f32x4 acc[2]) {
    const int rl = lane & 15, kq = lane >> 4;
#pragma unroll
    for (int tr = 0; tr < 2; ++tr) {
        const int r = tr*16 + rl;
        const u16* arow = act + r*HD;
        f32x4 a = {0.f,0.f,0.f,0.f};
#pragma unroll
        for (int kk = 0; kk < 4; ++kk) {
            bf16x8 bf = *reinterpret_cast<const bf16x8*>(arow + SWZ(r, kk*32 + kq*8));
            a = __builtin_amdgcn_mfma_f32_16x16x32_bf16(W[kk], bf, a, 0, 0, 0);
        }
        acc[tr] = a;
    }
}
__device__ __forceinline__ void gemm2(const u16* __restrict__ act,
                                      const bf16x8 (&Wx)[4], const bf16x8 (&Wy)[4],
                                      int lane, f32x4 accX[2], f32x4 accY[2]) {
    const int rl = lane & 15, kq = lane >> 4;
#pragma unroll
    for (int tr = 0; tr < 2; ++tr) {
        const int r = tr*16 + rl;
        const u16* arow = act + r*HD;
        f32x4 ax = {0.f,0.f,0.f,0.f}, ay = {0.f,0.f,0.f,0.f};
#pragma unroll
        for (int kk = 0; kk < 4; ++kk) {
            bf16x8 bf = *reinterpret_cast<const bf16x8*>(arow + SWZ(r, kk*32 + kq*8));
            ax = __builtin_amdgcn_mfma_f32_16x16x32_bf16(Wx[kk], bf, ax, 0, 0, 0);
            ay = __builtin_amdgcn_mfma_f32_16x16x32_bf16(Wy[kk], bf, ay, 0, 0, 0);
        }
        accX[tr] = ax; accY[tr] = ay;
    }
}

// ---- epilogues: lane holds 2 row-tiles, 4 consecutive channels ----
__device__ __forceinline__ void epiT(const f32x4 acc[2], const float b[4],
                                     u16* dst, int lane, int wid) {
    const int c0 = wid*16 + ((lane>>4)<<2);
    const int rl = lane & 15;
#pragma unroll
    for (int tr = 0; tr < 2; ++tr) {
        int r = tr*16 + rl;
        float v0 = tanh_f(acc[tr][0] + b[0]);
        float v1 = tanh_f(acc[tr][1] + b[1]);
        float v2 = tanh_f(acc[tr][2] + b[2]);
        float v3 = tanh_f(acc[tr][3] + b[3]);
        uint2 pk = { pack2(v0, v1), pack2(v2, v3) };
        *reinterpret_cast<uint2*>(dst + r*HD + SWZ(r, c0)) = pk;
    }
}
__device__ __forceinline__ void epiN(const f32x4 acc[2], const float b[4],
                                     u16* dst, int lane, int wid) {
    const int c0 = wid*16 + ((lane>>4)<<2);
    const int rl = lane & 15;
#pragma unroll
    for (int tr = 0; tr < 2; ++tr) {
        int r = tr*16 + rl;
        uint2 pk = { pack2(acc[tr][0]+b[0], acc[tr][1]+b[1]),
                     pack2(acc[tr][2]+b[2], acc[tr][3]+b[3]) };
        *reinterpret_cast<uint2*>(dst + r*HD + SWZ(r, c0)) = pk;
    }
}
__device__ __forceinline__ void epiF(const f32x4 acc[2], const float* __restrict__ bias,
                                     float* dst, int lane, int wid) {
    const int c0 = wid*16 + ((lane>>4)<<2);
    const int rl = lane & 15;
    float4 b4 = *reinterpret_cast<const float4*>(bias + c0);
#pragma unroll
    for (int tr = 0; tr < 2; ++tr) {
        int r = tr*16 + rl;
        float4 v = { acc[tr][0]+b4.x, acc[tr][1]+b4.y, acc[tr][2]+b4.z, acc[tr][3]+b4.w };
        *reinterpret_cast<float4*>(dst + r*HD + c0) = v;
    }
}

// ---- prologue GEMM over Xc (lda=256) ----
__device__ __forceinline__ void gemmX(const u16* __restrict__ Xc, int kBase,
                                      const u16* __restrict__ img,
                                      int lane, int wid, f32x4 acc[2], bool init) {
    bf16x8 W[4]; loadW(img, lane, wid, W);
    const int rl = lane & 15, kq = lane >> 4;
#pragma unroll
    for (int tr = 0; tr < 2; ++tr) {
        const int r = tr*16 + rl;
        const u16* arow = Xc + r*256;
        f32x4 a = init ? f32x4{0.f,0.f,0.f,0.f} : acc[tr];
#pragma unroll
        for (int kk = 0; kk < 4; ++kk) {
            bf16x8 bf = *reinterpret_cast<const bf16x8*>(arow + SWZ(r, kBase + kk*32 + kq*8));
            a = __builtin_amdgcn_mfma_f32_16x16x32_bf16(W[kk], bf, a, 0, 0, 0);
        }
        acc[tr] = a;
    }
}

// ---- LN + relu + 2-wide head; 8 lanes/row, params staged in LDS ----
__device__ __forceinline__ void head_ln(const u16* __restrict__ src,
                                        const float* __restrict__ gL, const float* __restrict__ bL,
                                        const float* __restrict__ w2a, const float* __restrict__ w2b,
                                        float b20, float b21, int elu, int off, int idx,
                                        float* __restrict__ outStage)
{
    int row = idx >> 3, sub = idx & 7;
    int c0 = sub * 16;
    uint4 p0 = *reinterpret_cast<const uint4*>(src + row*HD + SWZ(row, c0));
    uint4 p1 = *reinterpret_cast<const uint4*>(src + row*HD + SWZ(row, c0+8));
    float v[16];
    v[0]=bf2f(p0.x); v[1]=bf2f(p0.x>>16); v[2]=bf2f(p0.y); v[3]=bf2f(p0.y>>16);
    v[4]=bf2f(p0.z); v[5]=bf2f(p0.z>>16); v[6]=bf2f(p0.w); v[7]=bf2f(p0.w>>16);
    v[8]=bf2f(p1.x); v[9]=bf2f(p1.x>>16); v[10]=bf2f(p1.y); v[11]=bf2f(p1.y>>16);
    v[12]=bf2f(p1.z); v[13]=bf2f(p1.z>>16); v[14]=bf2f(p1.w); v[15]=bf2f(p1.w>>16);
    float s = 0.f, sq = 0.f;
#pragma unroll
    for (int i = 0; i < 16; ++i){ s += v[i]; sq += v[i]*v[i]; }
    s += __shfl_xor(s,1); sq += __shfl_xor(sq,1);
    s += __shfl_xor(s,2); sq += __shfl_xor(sq,2);
    s += __shfl_xor(s,4); sq += __shfl_xor(sq,4);
    float mu = s * (1.f/128.f);
    float rstd = rsqrtf(sq*(1.f/128.f) - mu*mu + LN_EPS);
    float a0 = 0.f, a1 = 0.f;
#pragma unroll
    for (int i = 0; i < 16; ++i){
        int c = c0 + i;
        float h = (v[i]-mu)*rstd*gL[c] + bL[c];
        h = fmaxf(h, 0.f);
        a0 += h * w2a[c]; a1 += h * w2b[c];
    }
    a0 += __shfl_xor(a0,1); a1 += __shfl_xor(a1,1);
    a0 += __shfl_xor(a0,2); a1 += __shfl_xor(a1,2);
    a0 += __shfl_xor(a0,4); a1 += __shfl_xor(a1,4);
    if (sub == 0){
        a0 += b20; a1 += b21;
        if (elu){
            a0 = (a0 > 0.f ? a0 : __expf(a0)-1.f) + 1.001f;
            a1 = (a1 > 0.f ? a1 : __expf(a1)-1.f) + 1.001f;
        }
        outStage[row*4 + off]   = a0;
        outStage[row*4 + off+1] = a1;
    }
}

// ---------- weight image prep: f32 -> bf16, transposed, swizzled ----------
__global__ void prep_w(const float* __restrict__ fw1, const float* __restrict__ fw2,
                       const float* __restrict__ fw3, const float* __restrict__ gw1,
                       const float* __restrict__ gw2, const float* __restrict__ dw1,
                       const float* __restrict__ sw1, const float* __restrict__ aw,
                       const float* __restrict__ pw1, u16* __restrict__ ws)
{
    int img = blockIdx.y;
    int idx = blockIdx.x * 256 + threadIdx.x;   // 0..16383
    int k = idx >> 7, j = idx & 127;
    const float* W = fw1; int sr = k;
    switch (img) {
        case 0: W = fw1; break;  case 1: W = fw2; break;  case 2: W = fw3; break;
        case 3: W = gw1; break;  case 4: W = gw2; break;
        case 5: W = dw1; break;  case 6: W = sw1; break;
        case 7: W = aw;  break;  case 8: W = aw;  sr = k + 128; break;
        case 9: W = pw1; break;  case 10: W = pw1; sr = k + 128; break;
    }
    ws[(size_t)img*16384 + j*128 + SWZ(j, k)] = f2bf(W[(size_t)sr*128 + j]);
}

// ---------- final output reorder: ws [blk][tt][row][4] -> loc_out [gr][tt][4] ----------
__global__ void reorder_out(const float* __restrict__ wsOut, float* __restrict__ outp)
{
    __shared__ float tile[3840];
    int b = blockIdx.x;
    const float* src = wsOut + (size_t)b*3840;
#pragma unroll
    for (int j = 0; j < 15; ++j) {
        int idx = j*256 + threadIdx.x;        // tt*128 + row*4 + c
        int tt = idx >> 7, rc = idx & 127;
        int row = rc >> 2, c = idx & 3;
        tile[row*120 + tt*4 + c] = src[idx];
    }
    __syncthreads();
    float* dst = outp + (size_t)b*3840;
#pragma unroll
    for (int j = 0; j < 15; ++j) {
        int idx = j*256 + threadIdx.x;
        dst[idx] = tile[idx];
    }
}

// ---------- the fused persistent kernel ----------
__global__ __launch_bounds__(512, 1) void sde_fused(
    const float* __restrict__ lE, const float* __restrict__ gE,
    const float* __restrict__ noise,
    const float* __restrict__ aggr_b, const float* __restrict__ aggr_g, const float* __restrict__ aggr_be,
    const float* __restrict__ fw1, const float* __restrict__ fb1,
    const float* __restrict__ fb2, const float* __restrict__ fb3,
    const float* __restrict__ gw1, const float* __restrict__ gb1,
    const float* __restrict__ gb2, const float* __restrict__ gw3, const float* __restrict__ gb3,
    const float* __restrict__ db1, const float* __restrict__ dg, const float* __restrict__ dbe,
    const float* __restrict__ dw2, const float* __restrict__ db2,
    const float* __restrict__ sb1, const float* __restrict__ sg, const float* __restrict__ sbe,
    const float* __restrict__ sw2, const float* __restrict__ sb2,
    const float* __restrict__ pb1, const float* __restrict__ pg, const float* __restrict__ pbe,
    const float* __restrict__ pw2, const float* __restrict__ pb2,
    const unsigned char* __restrict__ pmask,
    const u16* __restrict__ wimg,
    float* __restrict__ wsOut,
    float* __restrict__ outp)
{
    // LDS: Yf/Xc @0 (16K) | Sb @16K | Ab @24K | Bb @32K | Cb @40K (8K each)
    //      params @48K (4.5K) | grow | outStage ; preLN f32 aliases Ab+Bb
    __shared__ __align__(16) unsigned char SMEM[54400];
    float* Yf   = (float*)SMEM;
    u16*  Xc    = (u16*)SMEM;
    u16*  Sb    = (u16*)(SMEM + 16384);
    u16*  Ab    = (u16*)(SMEM + 24576);
    u16*  Bb    = (u16*)(SMEM + 32768);
    u16*  Cb    = (u16*)(SMEM + 40960);
    float* preLN = (float*)(SMEM + 24576);
    float* pp   = (float*)(SMEM + 49152);   // 9 x 128 staged params
    float* grow = (float*)(SMEM + 53760);
    float* outStage = (float*)(SMEM + 53888); // 128 floats

    const int tid  = threadIdx.x;
    const int lane = tid & 63;
    const int wid  = tid >> 6;
    const int bid  = blockIdx.x;
    const int r0   = bid * RBLK;
    const int c0e  = wid*16 + ((lane>>4)<<2);

    // -------- stage params + Xc --------
    if (tid < 128) {
        pp[0*128+tid] = dg[tid];      pp[1*128+tid] = dbe[tid];
        pp[2*128+tid] = sg[tid];      pp[3*128+tid] = sbe[tid];
        pp[4*128+tid] = dw2[2*tid];   pp[5*128+tid] = dw2[2*tid+1];
        pp[6*128+tid] = sw2[2*tid];   pp[7*128+tid] = sw2[2*tid+1];
        pp[8*128+tid] = gw3[tid];
    }
#pragma unroll
    for (int i = 0; i < 2; ++i) {
        int gidx = i*512 + tid;             // 0..1023
        int r = gidx >> 5;
        int k = (gidx & 31) * 8;
        int gr = r0 + r;
        const float* src = (k < HD) ? (gE + (size_t)gr*HD + k)
                                    : (lE + (size_t)(gr & (Adim-1))*HD + (k - HD));
        float4 v0 = reinterpret_cast<const float4*>(src)[0];
        float4 v1 = reinterpret_cast<const float4*>(src)[1];
        uint4 pk = { pack2(v0.x, v0.y), pack2(v0.z, v0.w),
                     pack2(v1.x, v1.y), pack2(v1.z, v1.w) };
        *reinterpret_cast<uint4*>(Xc + r*256 + SWZ(r, k)) = pk;
    }
    __syncthreads();

    f32x4 acc[2];

    // -------- pi head --------
    gemmX(Xc, 0,   wimg + 10*16384, lane, wid, acc, true);   // ge part
    gemmX(Xc, 128, wimg + 9*16384,  lane, wid, acc, false);  // le part
    epiF(acc, pb1, preLN, lane, wid);
    __syncthreads();
    {
        int row = tid >> 4, sub = tid & 15;
        int c0 = sub * 8;
        const float* yr = preLN + row*HD + c0;
        float v[8]; float s = 0.f, sq = 0.f;
#pragma unroll
        for (int i = 0; i < 8; ++i){ float x = yr[i]; v[i] = x; s += x; sq += x*x; }
        s += __shfl_xor(s,1); sq += __shfl_xor(sq,1);
        s += __shfl_xor(s,2); sq += __shfl_xor(sq,2);
        s += __shfl_xor(s,4); sq += __shfl_xor(sq,4);
        s += __shfl_xor(s,8); sq += __shfl_xor(sq,8);
        float mu = s*(1.f/128.f);
        float rstd = rsqrtf(sq*(1.f/128.f) - mu*mu + LN_EPS);
        float a0 = 0.f;
#pragma unroll
        for (int i = 0; i < 8; ++i){
            int cc = c0 + i;
            float h = (v[i]-mu)*rstd*pg[cc] + pbe[cc];
            a0 += fmaxf(h, 0.f) * pw2[cc];
        }
        a0 += __shfl_xor(a0,1); a0 += __shfl_xor(a0,2);
        a0 += __shfl_xor(a0,4); a0 += __shfl_xor(a0,8);
        if (sub == 0) {
            int gr = r0 + row;
            outp[PI_OFF + (size_t)(gr & (Adim-1))*6 + (gr >> 12)] = a0 + pb2[0];
        }
    }
    if (tid < RBLK) {              // reg_mask (rows with m==0)
        int gr = r0 + tid;
        if (gr < Adim) {
            const unsigned char* pm = pmask + (size_t)gr*50 + 20;
            float* o = outp + MASK_OFF + (size_t)gr*TSTEPS;
#pragma unroll
            for (int i = 0; i < TSTEPS; ++i) o[i] = pm[i] ? 0.f : 1.f;
        }
    }
    __syncthreads();

    // -------- aggr head -> h0 --------
    gemmX(Xc, 0,   wimg + 7*16384, lane, wid, acc, true);
    gemmX(Xc, 128, wimg + 8*16384, lane, wid, acc, false);
    __syncthreads();               // Xc reads done before preLN write? (preLN != Xc) -- keep for epi order
    epiF(acc, aggr_b, preLN, lane, wid);
    __syncthreads();
    {
        int row = tid >> 4, sub = tid & 15;
        int c0 = sub * 8;
        const float* yr = preLN + row*HD + c0;
        float v[8]; float s = 0.f, sq = 0.f;
#pragma unroll
        for (int i = 0; i < 8; ++i){ float x = yr[i]; v[i] = x; s += x; sq += x*x; }
        s += __shfl_xor(s,1); sq += __shfl_xor(sq,1);
        s += __shfl_xor(s,2); sq += __shfl_xor(sq,2);
        s += __shfl_xor(s,4); sq += __shfl_xor(sq,4);
        s += __shfl_xor(s,8); sq += __shfl_xor(sq,8);
        float mu = s*(1.f/128.f);
        float rstd = rsqrtf(sq*(1.f/128.f) - mu*mu + LN_EPS);
#pragma unroll
        for (int i = 0; i < 8; ++i){
            int cc = c0 + i;
            float h = (v[i]-mu)*rstd*aggr_g[cc] + aggr_be[cc];
            v[i] = fmaxf(h, 0.f);
        }
        __syncthreads();           // all preLN reads done before Yf (aliases Xc) write
        *reinterpret_cast<float4*>(Yf + row*HD + c0)     = *(float4*)&v[0];
        *reinterpret_cast<float4*>(Yf + row*HD + c0 + 4) = *(float4*)&v[4];
        uint4 pk = { pack2(v[0],v[1]), pack2(v[2],v[3]),
                     pack2(v[4],v[5]), pack2(v[6],v[7]) };
        *reinterpret_cast<uint4*>(&Sb[row*HD + SWZ(row, c0)]) = pk;
    }
    __syncthreads();

    // -------- loop weights into registers --------
    bf16x8 WF1[4], WG1[4], WF2[4], WG2[4], WF3[4], WD1[4], WS1[4];
    loadW(wimg + 0*16384, lane, wid, WF1);
    loadW(wimg + 3*16384, lane, wid, WG1);
    loadW(wimg + 1*16384, lane, wid, WF2);
    loadW(wimg + 4*16384, lane, wid, WG2);
    loadW(wimg + 2*16384, lane, wid, WF3);
    loadW(wimg + 5*16384, lane, wid, WD1);
    loadW(wimg + 6*16384, lane, wid, WS1);

    float fb2c[4], gb2c[4], fb3c[4], db1c[4], sb1c[4];
    float fb1c[4], gb1c[4], fw1s[4], fw1cc[4], gw1s[4], gw1cc[4];
#pragma unroll
    for (int q = 0; q < 4; ++q) {
        int c = c0e + q;
        fb2c[q]=fb2[c]; gb2c[q]=gb2[c]; fb3c[q]=fb3[c]; db1c[q]=db1[c]; sb1c[q]=sb1[c];
        fb1c[q]=fb1[c]; gb1c[q]=gb1[c];
        fw1s[q]=fw1[128*HD+c]; fw1cc[q]=fw1[129*HD+c];
        gw1s[q]=gw1[128*HD+c]; gw1cc[q]=gw1[129*HD+c];
    }
    const float db20 = db2[0], db21 = db2[1];
    const float sb20 = sb2[0], sb21 = sb2[1];
    const float gb3v = gb3[0];

    // -------- Euler-Maruyama scan --------
    for (int tt = 0; tt < TSTEPS; ++tt) {
        float t = tt * DT_C;
        float st = __sinf(t), ct = __cosf(t);
        float bF[4], bG[4];
#pragma unroll
        for (int q = 0; q < 4; ++q) {
            bF[q] = fb1c[q] + st*fw1s[q] + ct*fw1cc[q];
            bG[q] = gb1c[q] + st*gw1s[q] + ct*gw1cc[q];
        }
        // P1: flush prev outStage (coalesced) + noise prefetch + L1f,L1g
        if (tt > 0 && tid < 128)
            wsOut[((size_t)bid*TSTEPS + (tt-1))*128 + tid] = outStage[tid];
        float4 nz0, nz1;
        {
            const float* np = noise + ((size_t)tt*NROWS + r0)*HD + (size_t)tid*8;
            nz0 = reinterpret_cast<const float4*>(np)[0];
            nz1 = reinterpret_cast<const float4*>(np)[1];
        }
        {
            f32x4 aF[2], aG[2];
            gemm2(Sb, WF1, WG1, lane, aF, aG);
            epiT(aF, bF, Ab, lane, wid);
            epiT(aG, bG, Bb, lane, wid);
        }
        __syncthreads();
        // P2: L2f(Ab->Cb), L2g(Bb->Sb)
        {
            f32x4 a1[2];
            gemm1(Ab, WF2, lane, a1);
            epiT(a1, fb2c, Cb, lane, wid);
            gemm1(Bb, WG2, lane, a1);
            epiT(a1, gb2c, Sb, lane, wid);
        }
        __syncthreads();
        // P3: L3f drift (Cb -> Bb) + gw3 GEMV (Sb -> grow)
        {
            f32x4 a1[2];
            gemm1(Cb, WF3, lane, a1);
            epiN(a1, fb3c, Bb, lane, wid);
        }
        {
            int row = tid >> 4, sub = tid & 15;
            int cb = sub * 8;
            uint4 pk = *reinterpret_cast<const uint4*>(Sb + row*HD + SWZ(row, cb));
            const float* g3 = pp + 8*128 + cb;
            float s = bf2f(pk.x)*g3[0] + bf2f(pk.x>>16)*g3[1]
                    + bf2f(pk.y)*g3[2] + bf2f(pk.y>>16)*g3[3]
                    + bf2f(pk.z)*g3[4] + bf2f(pk.z>>16)*g3[5]
                    + bf2f(pk.w)*g3[6] + bf2f(pk.w>>16)*g3[7];
            s += __shfl_xor(s,1); s += __shfl_xor(s,2);
            s += __shfl_xor(s,4); s += __shfl_xor(s,8);
            if (sub == 0) grow[row] = sigm_f(s + gb3v);
        }
        __syncthreads();
        // P4: Euler update (full-width, coalesced)
        {
            int r  = tid >> 4;
            int k0 = (tid & 15) * 8;
            int sk = SWZ(r, k0);
            uint4 dpk = *reinterpret_cast<const uint4*>(Bb + r*HD + sk);
            float4 y0 = *reinterpret_cast<const float4*>(Yf + r*HD + k0);
            float4 y1 = *reinterpret_cast<const float4*>(Yf + r*HD + k0 + 4);
            float g = grow[r] * SQDT_C;
            y0.x += bf2f(dpk.x)     * DT_C + g*nz0.x;
            y0.y += bf2f(dpk.x>>16) * DT_C + g*nz0.y;
            y0.z += bf2f(dpk.y)     * DT_C + g*nz0.z;
            y0.w += bf2f(dpk.y>>16) * DT_C + g*nz0.w;
            y1.x += bf2f(dpk.z)     * DT_C + g*nz1.x;
            y1.y += bf2f(dpk.z>>16) * DT_C + g*nz1.y;
            y1.z += bf2f(dpk.w)     * DT_C + g*nz1.z;
            y1.w += bf2f(dpk.w>>16) * DT_C + g*nz1.w;
            *reinterpret_cast<float4*>(Yf + r*HD + k0)     = y0;
            *reinterpret_cast<float4*>(Yf + r*HD + k0 + 4) = y1;
            uint4 s4 = { pack2(y0.x,y0.y), pack2(y0.z,y0.w),
                         pack2(y1.x,y1.y), pack2(y1.z,y1.w) };
            *reinterpret_cast<uint4*>(Sb + r*HD + sk) = s4;
        }
        __syncthreads();
        // P5: D1,S1 (shared input Sb)
        {
            f32x4 aD[2], aS[2];
            gemm2(Sb, WD1, WS1, lane, aD, aS);
            epiN(aD, db1c, Ab, lane, wid);
            epiN(aS, sb1c, Cb, lane, wid);
        }
        __syncthreads();
        // P6: two heads in parallel on disjoint wave halves
        if (tid < 256)
            head_ln(Ab, pp+0*128, pp+1*128, pp+4*128, pp+5*128, db20, db21, 0, 0, tid, outStage);
        else
            head_ln(Cb, pp+2*128, pp+3*128, pp+6*128, pp+7*128, sb20, sb21, 1, 2, tid-256, outStage);
        __syncthreads();
    }
    if (tid < 128)
        wsOut[((size_t)bid*TSTEPS + (TSTEPS-1))*128 + tid] = outStage[tid];
}

extern "C" void kernel_launch(void* const* d_in, const int* in_sizes, int n_in,
                              void* d_out, int out_size, void* d_ws, size_t ws_size,
                              hipStream_t stream) {
    const float* lE      = (const float*)d_in[0];
    const float* gE      = (const float*)d_in[1];
    const float* noise   = (const float*)d_in[2];
    const float* aggr_w  = (const float*)d_in[3];
    const float* aggr_b  = (const float*)d_in[4];
    const float* aggr_g  = (const float*)d_in[5];
    const float* aggr_be = (const float*)d_in[6];
    const float* fw1 = (const float*)d_in[7];
    const float* fb1 = (const float*)d_in[8];
    const float* fw2 = (const float*)d_in[9];
    const float* fb2 = (const float*)d_in[10];
    const float* fw3 = (const float*)d_in[11];
    const float* fb3 = (const float*)d_in[12];
    const float* gw1 = (const float*)d_in[13];
    const float* gb1 = (const float*)d_in[14];
    const float* gw2 = (const float*)d_in[15];
    const float* gb2 = (const float*)d_in[16];
    const float* gw3 = (const float*)d_in[17];
    const float* gb3 = (const float*)d_in[18];
    const float* dw1 = (const float*)d_in[19];
    const float* db1 = (const float*)d_in[20];
    const float* dg  = (const float*)d_in[21];
    const float* dbe = (const float*)d_in[22];
    const float* dw2 = (const float*)d_in[23];
    const float* db2 = (const float*)d_in[24];
    const float* sw1 = (const float*)d_in[25];
    const float* sb1 = (const float*)d_in[26];
    const float* sg  = (const float*)d_in[27];
    const float* sbe = (const float*)d_in[28];
    const float* sw2 = (const float*)d_in[29];
    const float* sb2 = (const float*)d_in[30];
    const float* pw1 = (const float*)d_in[31];
    const float* pb1 = (const float*)d_in[32];
    const float* pg  = (const float*)d_in[33];
    const float* pbe = (const float*)d_in[34];
    const float* pw2 = (const float*)d_in[35];
    const float* pb2 = (const float*)d_in[36];
    const unsigned char* pmask = (const unsigned char*)d_in[37];
    float* outp = (float*)d_out;
    u16* wimg = (u16*)d_ws;                                  // 352 KB
    float* wsOut = (float*)((char*)d_ws + 360448);           // 768*3840 floats = 11.8 MB

    prep_w<<<dim3(64, 11), 256, 0, stream>>>(fw1, fw2, fw3, gw1, gw2, dw1, sw1,
                                             aggr_w, pw1, wimg);
    sde_fused<<<NBLKS, 512, 0, stream>>>(
        lE, gE, noise, aggr_b, aggr_g, aggr_be,
        fw1, fb1, fb2, fb3,
        gw1, gb1, gb2, gw3, gb3,
        db1, dg, dbe, dw2, db2,
        sb1, sg, sbe, sw2, sb2,
        pb1, pg, pbe, pw2, pb2,
        pmask, wimg, wsOut, outp);
    reorder_out<<<NBLKS, 256, 0, stream>>>(wsOut, outp);
}

// Round 4
// 593.463 us; speedup vs baseline: 2.7635x; 1.0366x over previous
//
#include <hip/hip_runtime.h>

#define Adim 4096
#define HD 128
#define TSTEPS 30
#define NROWS 24576
#define RBLK 32
#define NBLKS 768           // NROWS / RBLK
#define DT_C 0.2f
#define SQDT_C 0.44721359549995794f
#define LN_EPS 1e-5f

#define PI_OFF   2949120    // 6*4096*30*4
#define MASK_OFF 2973696    // PI_OFF + 24576

typedef unsigned short u16;
typedef __bf16 bf16x8 __attribute__((ext_vector_type(8)));
typedef float f32x4 __attribute__((ext_vector_type(4)));

__device__ __forceinline__ u16 f2bf(float x){
    unsigned u = __builtin_bit_cast(unsigned, x);
    u = (u + 0x7fffu + ((u >> 16) & 1u)) >> 16;
    return (u16)u;
}
__device__ __forceinline__ float bf2f(unsigned h){
    unsigned u = (h & 0xffffu) << 16;
    return __builtin_bit_cast(float, u);
}
__device__ __forceinline__ unsigned pack2(float a, float b){
    unsigned r;
    asm("v_cvt_pk_bf16_f32 %0, %1, %2" : "=v"(r) : "v"(a), "v"(b));
    return r;
}
__device__ __forceinline__ float tanh_f(float x){
    return 1.0f - 2.0f / (1.0f + __expf(2.0f * x));
}
__device__ __forceinline__ float sigm_f(float x){
    return 1.0f / (1.0f + __expf(-x));
}
#define SWZ(r,k) ((k) ^ (((r)&7)<<3))

#define MFMA(A,B,C) __builtin_amdgcn_mfma_f32_16x16x32_bf16(A, B, C, 0, 0, 0)

// ---- per-wave weight fragments: 16 output channels per wave ----
__device__ __forceinline__ void loadW(const u16* __restrict__ img, int lane, int wid,
                                      bf16x8 W[4]) {
    const int c = wid*16 + (lane & 15);
    const int kq = lane >> 4;
#pragma unroll
    for (int kk = 0; kk < 4; ++kk)
        W[kk] = *reinterpret_cast<const bf16x8*>(img + c*HD + SWZ(c, kk*32 + kq*8));
}

// ---- GEMMs (swapped): D[c][r] = sum_k W[c][k] act[r][k]; 32 rows = 2 tiles ----
__device__ __forceinline__ void gemm1(const u16* __restrict__ act, const bf16x8 (&W)[4],
                                      int lane, f32x4 acc[2]) {
    const int rl = lane & 15, kq = lane >> 4;
#pragma unroll
    for (int tr = 0; tr < 2; ++tr) {
        const int r = tr*16 + rl;
        const u16* arow = act + r*HD;
        f32x4 a = {0.f,0.f,0.f,0.f};
#pragma unroll
        for (int kk = 0; kk < 4; ++kk) {
            bf16x8 bf = *reinterpret_cast<const bf16x8*>(arow + SWZ(r, kk*32 + kq*8));
            a = MFMA(W[kk], bf, a);
        }
        acc[tr] = a;
    }
}
__device__ __forceinline__ void gemm2(const u16* __restrict__ act,
                                      const bf16x8 (&Wx)[4], const bf16x8 (&Wy)[4],
                                      int lane, f32x4 accX[2], f32x4 accY[2]) {
    const int rl = lane & 15, kq = lane >> 4;
#pragma unroll
    for (int tr = 0; tr < 2; ++tr) {
        const int r = tr*16 + rl;
        const u16* arow = act + r*HD;
        f32x4 ax = {0.f,0.f,0.f,0.f}, ay = {0.f,0.f,0.f,0.f};
#pragma unroll
        for (int kk = 0; kk < 4; ++kk) {
            bf16x8 bf = *reinterpret_cast<const bf16x8*>(arow + SWZ(r, kk*32 + kq*8));
            ax = MFMA(Wx[kk], bf, ax);
            ay = MFMA(Wy[kk], bf, ay);
        }
        accX[tr] = ax; accY[tr] = ay;
    }
}
__device__ __forceinline__ void gemm4(const u16* __restrict__ act,
                                      const bf16x8 (&W1)[4], const bf16x8 (&W2)[4],
                                      const bf16x8 (&W3)[4], const bf16x8 (&W4)[4],
                                      int lane, f32x4 a1[2], f32x4 a2[2],
                                      f32x4 a3[2], f32x4 a4[2]) {
    const int rl = lane & 15, kq = lane >> 4;
#pragma unroll
    for (int tr = 0; tr < 2; ++tr) {
        const int r = tr*16 + rl;
        const u16* arow = act + r*HD;
        f32x4 x1={0.f,0.f,0.f,0.f}, x2={0.f,0.f,0.f,0.f};
        f32x4 x3={0.f,0.f,0.f,0.f}, x4={0.f,0.f,0.f,0.f};
#pragma unroll
        for (int kk = 0; kk < 4; ++kk) {
            bf16x8 bf = *reinterpret_cast<const bf16x8*>(arow + SWZ(r, kk*32 + kq*8));
            x1 = MFMA(W1[kk], bf, x1);
            x2 = MFMA(W2[kk], bf, x2);
            x3 = MFMA(W3[kk], bf, x3);
            x4 = MFMA(W4[kk], bf, x4);
        }
        a1[tr]=x1; a2[tr]=x2; a3[tr]=x3; a4[tr]=x4;
    }
}

// ---- epilogues: lane holds 2 row-tiles, 4 consecutive channels ----
__device__ __forceinline__ void epiT(const f32x4 acc[2], const float b[4],
                                     u16* dst, int lane, int wid) {
    const int c0 = wid*16 + ((lane>>4)<<2);
    const int rl = lane & 15;
#pragma unroll
    for (int tr = 0; tr < 2; ++tr) {
        int r = tr*16 + rl;
        float v0 = tanh_f(acc[tr][0] + b[0]);
        float v1 = tanh_f(acc[tr][1] + b[1]);
        float v2 = tanh_f(acc[tr][2] + b[2]);
        float v3 = tanh_f(acc[tr][3] + b[3]);
        uint2 pk = { pack2(v0, v1), pack2(v2, v3) };
        *reinterpret_cast<uint2*>(dst + r*HD + SWZ(r, c0)) = pk;
    }
}
__device__ __forceinline__ void epiN(const f32x4 acc[2], const float b[4],
                                     u16* dst, int lane, int wid) {
    const int c0 = wid*16 + ((lane>>4)<<2);
    const int rl = lane & 15;
#pragma unroll
    for (int tr = 0; tr < 2; ++tr) {
        int r = tr*16 + rl;
        uint2 pk = { pack2(acc[tr][0]+b[0], acc[tr][1]+b[1]),
                     pack2(acc[tr][2]+b[2], acc[tr][3]+b[3]) };
        *reinterpret_cast<uint2*>(dst + r*HD + SWZ(r, c0)) = pk;
    }
}
__device__ __forceinline__ void epiF(const f32x4 acc[2], const float* __restrict__ bias,
                                     float* dst, int lane, int wid) {
    const int c0 = wid*16 + ((lane>>4)<<2);
    const int rl = lane & 15;
    float4 b4 = *reinterpret_cast<const float4*>(bias + c0);
#pragma unroll
    for (int tr = 0; tr < 2; ++tr) {
        int r = tr*16 + rl;
        float4 v = { acc[tr][0]+b4.x, acc[tr][1]+b4.y, acc[tr][2]+b4.z, acc[tr][3]+b4.w };
        *reinterpret_cast<float4*>(dst + r*HD + c0) = v;
    }
}

// ---- prologue GEMM over Xc (lda=256) ----
__device__ __forceinline__ void gemmX(const u16* __restrict__ Xc, int kBase,
                                      const u16* __restrict__ img,
                                      int lane, int wid, f32x4 acc[2], bool init) {
    bf16x8 W[4]; loadW(img, lane, wid, W);
    const int rl = lane & 15, kq = lane >> 4;
#pragma unroll
    for (int tr = 0; tr < 2; ++tr) {
        const int r = tr*16 + rl;
        const u16* arow = Xc + r*256;
        f32x4 a = init ? f32x4{0.f,0.f,0.f,0.f} : acc[tr];
#pragma unroll
        for (int kk = 0; kk < 4; ++kk) {
            bf16x8 bf = *reinterpret_cast<const bf16x8*>(arow + SWZ(r, kBase + kk*32 + kq*8));
            a = MFMA(W[kk], bf, a);
        }
        acc[tr] = a;
    }
}

// ---- LN + relu + 2-wide head; 8 lanes/row; params float4 swizzled in LDS ----
__device__ __forceinline__ void head_ln(const u16* __restrict__ src,
                                        const float4* __restrict__ pp4,
                                        float b20, float b21, int elu, int off, int idx,
                                        float* __restrict__ outStage)
{
    int row = idx >> 3, sub = idx & 7;
    int c0 = sub * 16;
    uint4 p0 = *reinterpret_cast<const uint4*>(src + row*HD + SWZ(row, c0));
    uint4 p1 = *reinterpret_cast<const uint4*>(src + row*HD + SWZ(row, c0+8));
    float v[16];
    v[0]=bf2f(p0.x); v[1]=bf2f(p0.x>>16); v[2]=bf2f(p0.y); v[3]=bf2f(p0.y>>16);
    v[4]=bf2f(p0.z); v[5]=bf2f(p0.z>>16); v[6]=bf2f(p0.w); v[7]=bf2f(p0.w>>16);
    v[8]=bf2f(p1.x); v[9]=bf2f(p1.x>>16); v[10]=bf2f(p1.y); v[11]=bf2f(p1.y>>16);
    v[12]=bf2f(p1.z); v[13]=bf2f(p1.z>>16); v[14]=bf2f(p1.w); v[15]=bf2f(p1.w>>16);
    float s = 0.f, sq = 0.f;
#pragma unroll
    for (int i = 0; i < 16; ++i){ s += v[i]; sq += v[i]*v[i]; }
    s += __shfl_xor(s,1); sq += __shfl_xor(sq,1);
    s += __shfl_xor(s,2); sq += __shfl_xor(sq,2);
    s += __shfl_xor(s,4); sq += __shfl_xor(sq,4);
    float mu = s * (1.f/128.f);
    float rstd = rsqrtf(sq*(1.f/128.f) - mu*mu + LN_EPS);
    float a0 = 0.f, a1 = 0.f;
#pragma unroll
    for (int i = 0; i < 16; ++i){
        float4 p = pp4[(c0 + i) ^ sub];
        float h = (v[i]-mu)*rstd*p.x + p.y;
        h = fmaxf(h, 0.f);
        a0 += h * p.z; a1 += h * p.w;
    }
    a0 += __shfl_xor(a0,1); a1 += __shfl_xor(a1,1);
    a0 += __shfl_xor(a0,2); a1 += __shfl_xor(a1,2);
    a0 += __shfl_xor(a0,4); a1 += __shfl_xor(a1,4);
    if (sub == 0){
        a0 += b20; a1 += b21;
        if (elu){
            a0 = (a0 > 0.f ? a0 : __expf(a0)-1.f) + 1.001f;
            a1 = (a1 > 0.f ? a1 : __expf(a1)-1.f) + 1.001f;
        }
        outStage[row*4 + off]   = a0;
        outStage[row*4 + off+1] = a1;
    }
}

// ---------- weight image prep: f32 -> bf16, transposed, swizzled ----------
__global__ void prep_w(const float* __restrict__ fw1, const float* __restrict__ fw2,
                       const float* __restrict__ fw3, const float* __restrict__ gw1,
                       const float* __restrict__ gw2, const float* __restrict__ dw1,
                       const float* __restrict__ sw1, const float* __restrict__ aw,
                       const float* __restrict__ pw1, u16* __restrict__ ws)
{
    int img = blockIdx.y;
    int idx = blockIdx.x * 256 + threadIdx.x;   // 0..16383
    int k = idx >> 7, j = idx & 127;
    const float* W = fw1; int sr = k;
    switch (img) {
        case 0: W = fw1; break;  case 1: W = fw2; break;  case 2: W = fw3; break;
        case 3: W = gw1; break;  case 4: W = gw2; break;
        case 5: W = dw1; break;  case 6: W = sw1; break;
        case 7: W = aw;  break;  case 8: W = aw;  sr = k + 128; break;
        case 9: W = pw1; break;  case 10: W = pw1; sr = k + 128; break;
    }
    ws[(size_t)img*16384 + j*128 + SWZ(j, k)] = f2bf(W[(size_t)sr*128 + j]);
}

// ---------- final output reorder: ws [blk][tt][row][4] -> loc_out [gr][tt][4] ----------
__global__ void reorder_out(const float* __restrict__ wsOut, float* __restrict__ outp)
{
    __shared__ float tile[3840];
    int b = blockIdx.x;
    const float* src = wsOut + (size_t)b*3840;
#pragma unroll
    for (int j = 0; j < 15; ++j) {
        int idx = j*256 + threadIdx.x;        // tt*128 + row*4 + c
        int tt = idx >> 7, rc = idx & 127;
        int row = rc >> 2, c = idx & 3;
        tile[row*120 + tt*4 + c] = src[idx];
    }
    __syncthreads();
    float* dst = outp + (size_t)b*3840;
#pragma unroll
    for (int j = 0; j < 15; ++j) {
        int idx = j*256 + threadIdx.x;
        dst[idx] = tile[idx];
    }
}

// ---------- the fused persistent kernel ----------
__global__ __launch_bounds__(512, 2) void sde_fused(
    const float* __restrict__ lE, const float* __restrict__ gE,
    const float* __restrict__ noise,
    const float* __restrict__ aggr_b, const float* __restrict__ aggr_g, const float* __restrict__ aggr_be,
    const float* __restrict__ fw1, const float* __restrict__ fb1,
    const float* __restrict__ fb2, const float* __restrict__ fb3,
    const float* __restrict__ gw1, const float* __restrict__ gb1,
    const float* __restrict__ gb2, const float* __restrict__ gw3, const float* __restrict__ gb3,
    const float* __restrict__ db1, const float* __restrict__ dg, const float* __restrict__ dbe,
    const float* __restrict__ dw2, const float* __restrict__ db2,
    const float* __restrict__ sb1, const float* __restrict__ sg, const float* __restrict__ sbe,
    const float* __restrict__ sw2, const float* __restrict__ sb2,
    const float* __restrict__ pb1, const float* __restrict__ pg, const float* __restrict__ pbe,
    const float* __restrict__ pw2, const float* __restrict__ pb2,
    const unsigned char* __restrict__ pmask,
    const u16* __restrict__ wimg,
    float* __restrict__ wsOut,
    float* __restrict__ outp)
{
    // LDS: Sb@0 Ab@8K Bb@16K Cb@24K Fb@32K Db@40K Eb@48K (8K each)
    //      pp4 @56K (4K: d 2K + s 2K) | outStage @60K (512B)
    // prologue aliases: Xc (16K) @40K (Db+Eb); preLN (16K f32) @8K (Ab+Bb)
    __shared__ __align__(16) unsigned char SMEM[61952];
    u16*  Sb    = (u16*)SMEM;
    u16*  Ab    = (u16*)(SMEM + 8192);
    u16*  Bb    = (u16*)(SMEM + 16384);
    u16*  Cb    = (u16*)(SMEM + 24576);
    u16*  Fb    = (u16*)(SMEM + 32768);
    u16*  Db    = (u16*)(SMEM + 40960);
    u16*  Eb    = (u16*)(SMEM + 49152);
    float4* ppd = (float4*)(SMEM + 57344);
    float4* pps = (float4*)(SMEM + 59392);
    float* outStage = (float*)(SMEM + 61440);
    u16*  Xc    = (u16*)(SMEM + 40960);
    float* preLN = (float*)(SMEM + 8192);

    const int tid  = threadIdx.x;
    const int lane = tid & 63;
    const int wid  = tid >> 6;
    const int bid  = blockIdx.x;
    const int r0   = bid * RBLK;
    const int c0e  = wid*16 + ((lane>>4)<<2);   // this lane's 4 output channels

    // -------- stage params + Xc --------
    if (tid < 128) {
        int cs = tid ^ ((tid >> 4) & 7);
        ppd[cs] = make_float4(dg[tid], dbe[tid], dw2[2*tid], dw2[2*tid+1]);
        pps[cs] = make_float4(sg[tid], sbe[tid], sw2[2*tid], sw2[2*tid+1]);
    }
#pragma unroll
    for (int i = 0; i < 2; ++i) {
        int gidx = i*512 + tid;             // 0..1023
        int r = gidx >> 5;
        int k = (gidx & 31) * 8;
        int gr = r0 + r;
        const float* src = (k < HD) ? (gE + (size_t)gr*HD + k)
                                    : (lE + (size_t)(gr & (Adim-1))*HD + (k - HD));
        float4 v0 = reinterpret_cast<const float4*>(src)[0];
        float4 v1 = reinterpret_cast<const float4*>(src)[1];
        uint4 pk = { pack2(v0.x, v0.y), pack2(v0.z, v0.w),
                     pack2(v1.x, v1.y), pack2(v1.z, v1.w) };
        *reinterpret_cast<uint4*>(Xc + r*256 + SWZ(r, k)) = pk;
    }
    __syncthreads();

    f32x4 acc[2];

    // -------- pi head --------
    gemmX(Xc, 0,   wimg + 10*16384, lane, wid, acc, true);   // ge part
    gemmX(Xc, 128, wimg + 9*16384,  lane, wid, acc, false);  // le part
    epiF(acc, pb1, preLN, lane, wid);
    __syncthreads();
    {
        int row = tid >> 4, sub = tid & 15;
        int c0 = sub * 8;
        const float* yr = preLN + row*HD + c0;
        float v[8]; float s = 0.f, sq = 0.f;
#pragma unroll
        for (int i = 0; i < 8; ++i){ float x = yr[i]; v[i] = x; s += x; sq += x*x; }
        s += __shfl_xor(s,1); sq += __shfl_xor(sq,1);
        s += __shfl_xor(s,2); sq += __shfl_xor(sq,2);
        s += __shfl_xor(s,4); sq += __shfl_xor(sq,4);
        s += __shfl_xor(s,8); sq += __shfl_xor(sq,8);
        float mu = s*(1.f/128.f);
        float rstd = rsqrtf(sq*(1.f/128.f) - mu*mu + LN_EPS);
        float a0 = 0.f;
#pragma unroll
        for (int i = 0; i < 8; ++i){
            int cc = c0 + i;
            float h = (v[i]-mu)*rstd*pg[cc] + pbe[cc];
            a0 += fmaxf(h, 0.f) * pw2[cc];
        }
        a0 += __shfl_xor(a0,1); a0 += __shfl_xor(a0,2);
        a0 += __shfl_xor(a0,4); a0 += __shfl_xor(a0,8);
        if (sub == 0) {
            int gr = r0 + row;
            outp[PI_OFF + (size_t)(gr & (Adim-1))*6 + (gr >> 12)] = a0 + pb2[0];
        }
    }
    if (tid < RBLK) {              // reg_mask (rows with m==0)
        int gr = r0 + tid;
        if (gr < Adim) {
            const unsigned char* pm = pmask + (size_t)gr*50 + 20;
            float* o = outp + MASK_OFF + (size_t)gr*TSTEPS;
#pragma unroll
            for (int i = 0; i < TSTEPS; ++i) o[i] = pm[i] ? 0.f : 1.f;
        }
    }
    __syncthreads();

    // -------- aggr head -> h0 --------
    gemmX(Xc, 0,   wimg + 7*16384, lane, wid, acc, true);
    gemmX(Xc, 128, wimg + 8*16384, lane, wid, acc, false);
    __syncthreads();
    epiF(acc, aggr_b, preLN, lane, wid);
    __syncthreads();

    float y0,y1,y2,y3,y4,y5,y6,y7;      // state in registers
    {
        int row = tid >> 4, sub = tid & 15;
        int c0 = sub * 8;
        const float* yr = preLN + row*HD + c0;
        float v[8]; float s = 0.f, sq = 0.f;
#pragma unroll
        for (int i = 0; i < 8; ++i){ float x = yr[i]; v[i] = x; s += x; sq += x*x; }
        s += __shfl_xor(s,1); sq += __shfl_xor(sq,1);
        s += __shfl_xor(s,2); sq += __shfl_xor(sq,2);
        s += __shfl_xor(s,4); sq += __shfl_xor(sq,4);
        s += __shfl_xor(s,8); sq += __shfl_xor(sq,8);
        float mu = s*(1.f/128.f);
        float rstd = rsqrtf(sq*(1.f/128.f) - mu*mu + LN_EPS);
#pragma unroll
        for (int i = 0; i < 8; ++i){
            int cc = c0 + i;
            float h = (v[i]-mu)*rstd*aggr_g[cc] + aggr_be[cc];
            v[i] = fmaxf(h, 0.f);
        }
        y0=v[0]; y1=v[1]; y2=v[2]; y3=v[3]; y4=v[4]; y5=v[5]; y6=v[6]; y7=v[7];
        uint4 pk = { pack2(v[0],v[1]), pack2(v[2],v[3]),
                     pack2(v[4],v[5]), pack2(v[6],v[7]) };
        *reinterpret_cast<uint4*>(&Sb[row*HD + SWZ(row, c0)]) = pk;
    }

    // -------- loop weights into registers --------
    bf16x8 WF1[4], WG1[4], WF2[4], WG2[4], WF3[4], WD1[4], WS1[4];
    loadW(wimg + 0*16384, lane, wid, WF1);
    loadW(wimg + 3*16384, lane, wid, WG1);
    loadW(wimg + 1*16384, lane, wid, WF2);
    loadW(wimg + 4*16384, lane, wid, WG2);
    loadW(wimg + 2*16384, lane, wid, WF3);
    loadW(wimg + 5*16384, lane, wid, WD1);
    loadW(wimg + 6*16384, lane, wid, WS1);

    float fb2c[4], gb2c[4], fb3c[4], db1c[4], sb1c[4];
    float fb1c[4], gb1c[4], fw1s[4], fw1cc[4], gw1s[4], gw1cc[4];
#pragma unroll
    for (int q = 0; q < 4; ++q) {
        int c = c0e + q;
        fb2c[q]=fb2[c]; gb2c[q]=gb2[c]; fb3c[q]=fb3[c]; db1c[q]=db1[c]; sb1c[q]=sb1[c];
        fb1c[q]=fb1[c]; gb1c[q]=gb1[c];
        fw1s[q]=fw1[128*HD+c]; fw1cc[q]=fw1[129*HD+c];
        gw1s[q]=gw1[128*HD+c]; gw1cc[q]=gw1[129*HD+c];
    }
    float g3r[8];
#pragma unroll
    for (int j = 0; j < 8; ++j) g3r[j] = gw3[(tid & 15)*8 + j];
    const float db20 = db2[0], db21 = db2[1];
    const float sb20 = sb2[0], sb21 = sb2[1];
    const float gb3v = gb3[0];

    float4 nz0, nz1;
    __syncthreads();

    // -------- PhA(0): L1f,L1g at t=0 + noise prefetch --------
    {
        float bF[4], bG[4];
#pragma unroll
        for (int q = 0; q < 4; ++q) { bF[q] = fb1c[q] + fw1cc[q]; bG[q] = gb1c[q] + gw1cc[q]; }
        f32x4 aF[2], aG[2];
        gemm2(Sb, WF1, WG1, lane, aF, aG);
        epiT(aF, bF, Ab, lane, wid);
        epiT(aG, bG, Bb, lane, wid);
        const float* np = noise + ((size_t)r0)*HD + (size_t)tid*8;
        nz0 = reinterpret_cast<const float4*>(np)[0];
        nz1 = reinterpret_cast<const float4*>(np)[1];
    }
    __syncthreads();

    // -------- Euler-Maruyama scan: 4 barriers/step --------
    for (int k = 0; k < TSTEPS; ++k) {
        // PhB: L2f(Ab->Cb), L2g(Bb->Fb) + heads for output k-1
        {
            f32x4 a1[2];
            gemm1(Ab, WF2, lane, a1);
            epiT(a1, fb2c, Cb, lane, wid);
            gemm1(Bb, WG2, lane, a1);
            epiT(a1, gb2c, Fb, lane, wid);
        }
        if (k) {
            if (tid < 256) head_ln(Db, ppd, db20, db21, 0, 0, tid, outStage);
            else           head_ln(Eb, pps, sb20, sb21, 1, 2, tid-256, outStage);
        }
        __syncthreads();
        // PhC: L3f drift (Cb -> Db) + gw3 GEMV (Fb -> reg)
        {
            f32x4 a1[2];
            gemm1(Cb, WF3, lane, a1);
            epiN(a1, fb3c, Db, lane, wid);
        }
        float growv;
        {
            int row = tid >> 4, sub = tid & 15;
            uint4 pk = *reinterpret_cast<const uint4*>(Fb + row*HD + SWZ(row, sub*8));
            float s = bf2f(pk.x)*g3r[0] + bf2f(pk.x>>16)*g3r[1]
                    + bf2f(pk.y)*g3r[2] + bf2f(pk.y>>16)*g3r[3]
                    + bf2f(pk.z)*g3r[4] + bf2f(pk.z>>16)*g3r[5]
                    + bf2f(pk.w)*g3r[6] + bf2f(pk.w>>16)*g3r[7];
            s += __shfl_xor(s,1); s += __shfl_xor(s,2);
            s += __shfl_xor(s,4); s += __shfl_xor(s,8);
            growv = sigm_f(s + gb3v);
        }
        __syncthreads();
        // PhD: Euler update (state regs) -> Sb
        {
            int row = tid >> 4, sub = tid & 15;
            int sk = SWZ(row, sub*8);
            uint4 dpk = *reinterpret_cast<const uint4*>(Db + row*HD + sk);
            float g = growv * SQDT_C;
            y0 += bf2f(dpk.x)     * DT_C + g*nz0.x;
            y1 += bf2f(dpk.x>>16) * DT_C + g*nz0.y;
            y2 += bf2f(dpk.y)     * DT_C + g*nz0.z;
            y3 += bf2f(dpk.y>>16) * DT_C + g*nz0.w;
            y4 += bf2f(dpk.z)     * DT_C + g*nz1.x;
            y5 += bf2f(dpk.z>>16) * DT_C + g*nz1.y;
            y6 += bf2f(dpk.w)     * DT_C + g*nz1.z;
            y7 += bf2f(dpk.w>>16) * DT_C + g*nz1.w;
            uint4 s4 = { pack2(y0,y1), pack2(y2,y3), pack2(y4,y5), pack2(y6,y7) };
            *reinterpret_cast<uint4*>(Sb + row*HD + sk) = s4;
        }
        __syncthreads();
        // PhA(k+1): L1f,L1g(t_{k+1}) + D1,S1 on new state; nz prefetch; flush
        if (k < TSTEPS-1) {
            float t = (k+1) * DT_C;
            float st = __sinf(t), ct = __cosf(t);
            float bF[4], bG[4];
#pragma unroll
            for (int q = 0; q < 4; ++q) {
                bF[q] = fb1c[q] + st*fw1s[q] + ct*fw1cc[q];
                bG[q] = gb1c[q] + st*gw1s[q] + ct*gw1cc[q];
            }
            f32x4 aF[2], aG[2], aD[2], aS[2];
            gemm4(Sb, WF1, WG1, WD1, WS1, lane, aF, aG, aD, aS);
            epiT(aF, bF, Ab, lane, wid);
            epiT(aG, bG, Bb, lane, wid);
            epiN(aD, db1c, Db, lane, wid);
            epiN(aS, sb1c, Eb, lane, wid);
            const float* np = noise + ((size_t)(k+1)*NROWS + r0)*HD + (size_t)tid*8;
            nz0 = reinterpret_cast<const float4*>(np)[0];
            nz1 = reinterpret_cast<const float4*>(np)[1];
            if (k >= 1 && tid < 128)
                wsOut[((size_t)bid*TSTEPS + (k-1))*128 + tid] = outStage[tid];
        } else {
            f32x4 aD[2], aS[2];
            gemm2(Sb, WD1, WS1, lane, aD, aS);
            epiN(aD, db1c, Db, lane, wid);
            epiN(aS, sb1c, Eb, lane, wid);
            if (tid < 128)
                wsOut[((size_t)bid*TSTEPS + (TSTEPS-2))*128 + tid] = outStage[tid];
        }
        __syncthreads();
    }
    // final heads (output TSTEPS-1)
    if (tid < 256) head_ln(Db, ppd, db20, db21, 0, 0, tid, outStage);
    else           head_ln(Eb, pps, sb20, sb21, 1, 2, tid-256, outStage);
    __syncthreads();
    if (tid < 128)
        wsOut[((size_t)bid*TSTEPS + (TSTEPS-1))*128 + tid] = outStage[tid];
}

extern "C" void kernel_launch(void* const* d_in, const int* in_sizes, int n_in,
                              void* d_out, int out_size, void* d_ws, size_t ws_size,
                              hipStream_t stream) {
    const float* lE      = (const float*)d_in[0];
    const float* gE      = (const float*)d_in[1];
    const float* noise   = (const float*)d_in[2];
    const float* aggr_w  = (const float*)d_in[3];
    const float* aggr_b  = (const float*)d_in[4];
    const float* aggr_g  = (const float*)d_in[5];
    const float* aggr_be = (const float*)d_in[6];
    const float* fw1 = (const float*)d_in[7];
    const float* fb1 = (const float*)d_in[8];
    const float* fw2 = (const float*)d_in[9];
    const float* fb2 = (const float*)d_in[10];
    const float* fw3 = (const float*)d_in[11];
    const float* fb3 = (const float*)d_in[12];
    const float* gw1 = (const float*)d_in[13];
    const float* gb1 = (const float*)d_in[14];
    const float* gw2 = (const float*)d_in[15];
    const float* gb2 = (const float*)d_in[16];
    const float* gw3 = (const float*)d_in[17];
    const float* gb3 = (const float*)d_in[18];
    const float* dw1 = (const float*)d_in[19];
    const float* db1 = (const float*)d_in[20];
    const float* dg  = (const float*)d_in[21];
    const float* dbe = (const float*)d_in[22];
    const float* dw2 = (const float*)d_in[23];
    const float* db2 = (const float*)d_in[24];
    const float* sw1 = (const float*)d_in[25];
    const float* sb1 = (const float*)d_in[26];
    const float* sg  = (const float*)d_in[27];
    const float* sbe = (const float*)d_in[28];
    const float* sw2 = (const float*)d_in[29];
    const float* sb2 = (const float*)d_in[30];
    const float* pw1 = (const float*)d_in[31];
    const float* pb1 = (const float*)d_in[32];
    const float* pg  = (const float*)d_in[33];
    const float* pbe = (const float*)d_in[34];
    const float* pw2 = (const float*)d_in[35];
    const float* pb2 = (const float*)d_in[36];
    const unsigned char* pmask = (const unsigned char*)d_in[37];
    float* outp = (float*)d_out;
    u16* wimg = (u16*)d_ws;                                  // 352 KB
    float* wsOut = (float*)((char*)d_ws + 360448);           // 768*3840 floats = 11.8 MB

    prep_w<<<dim3(64, 11), 256, 0, stream>>>(fw1, fw2, fw3, gw1, gw2, dw1, sw1,
                                             aggr_w, pw1, wimg);
    sde_fused<<<NBLKS, 512, 0, stream>>>(
        lE, gE, noise, aggr_b, aggr_g, aggr_be,
        fw1, fb1, fb2, fb3,
        gw1, gb1, gb2, gw3, gb3,
        db1, dg, dbe, dw2, db2,
        sb1, sg, sbe, sw2, sb2,
        pb1, pg, pbe, pw2, pb2,
        pmask, wimg, wsOut, outp);
    reorder_out<<<NBLKS, 256, 0, stream>>>(wsOut, outp);
}